// Round 13
// baseline (662.296 us; speedup 1.0000x reference)
//
#include <hip/hip_runtime.h>
#include <hip/hip_fp16.h>
#include <cstdint>
#include <cstddef>

// ---------------------------------------------------------------------------
// GIN (GINEConv x3) forward. f32 in/out; f16 internal; MFMA everywhere.
//   x16 = f16(x); h16 = x16@W_enc + b (enc_mfma)
//   CSR (deg padded even) -> sat{src,att} + attr16 (f16 edge_attr, slot order)
//   per layer: agg_mfma (ea via MFMA -> LDS; h16 gather) -> z16
//              mlp_mfma (16x16x32 f16) -> h16 (last layer: f32 d_out)
// ---------------------------------------------------------------------------

typedef _Float16 f16x8 __attribute__((ext_vector_type(8)));
typedef float    f32x4 __attribute__((ext_vector_type(4)));

// ---- packed-f32x2 atomic with compile-safe fallback (fallback tier only) ---
template <class T>
__device__ inline auto add2_impl(T* p, T v, int)
    -> decltype(unsafeAtomicAdd(p, v), void()) {
    unsafeAtomicAdd(p, v);
}
template <class T>
__device__ inline void add2_impl(T* p, T v, long) {
    unsafeAtomicAdd(&p->x, v.x);
    unsafeAtomicAdd(&p->y, v.y);
}
__device__ inline void atomic_add2(float* p, float x, float y) {
    add2_impl(reinterpret_cast<float2*>(p), make_float2(x, y), 0);
}

// ---------------------------------------------------------------------------
// CSR build
// ---------------------------------------------------------------------------
__global__ void init_arrays(int* __restrict__ cnt, int N, int* __restrict__ eids, int S)
{
    int i = blockIdx.x * blockDim.x + threadIdx.x;
    const int st = gridDim.x * blockDim.x;
    for (int j = i; j < N; j += st) cnt[j] = 0;
    for (int j = i; j < S; j += st) eids[j] = -1;
}

__global__ void hist_kernel(const int* __restrict__ ei, int* __restrict__ cnt, int E)
{
    int i = blockIdx.x * blockDim.x + threadIdx.x;
    const int st = gridDim.x * blockDim.x;
    for (; i < E; i += st) atomicAdd(&cnt[ei[E + i]], 1);
}

__global__ __launch_bounds__(256) void scan_pass1(
    const int* __restrict__ cnt, int* __restrict__ bsum, int N)
{
    __shared__ int part[256];
    const int t = threadIdx.x;
    const int base = blockIdx.x * 1024 + t * 4;
    int s = 0;
#pragma unroll
    for (int j = 0; j < 4; ++j) {
        int idx = base + j;
        if (idx < N) { int v = cnt[idx]; s += v + (v & 1); }
    }
    part[t] = s;
    __syncthreads();
    for (int d = 128; d > 0; d >>= 1) {
        if (t < d) part[t] += part[t + d];
        __syncthreads();
    }
    if (t == 0) bsum[blockIdx.x] = part[0];
}

__global__ __launch_bounds__(256) void scan_pass2(
    int* __restrict__ bsum, int* __restrict__ off, int NB, int N)
{
    __shared__ int sb[1024];
    const int t = threadIdx.x;
    for (int i = t; i < NB; i += 256) sb[i] = bsum[i];
    __syncthreads();
    if (t == 0) {
        int run = 0;
        for (int i = 0; i < NB; ++i) { int v = sb[i]; sb[i] = run; run += v; }
        off[N] = run;          // total padded slots S
    }
    __syncthreads();
    for (int i = t; i < NB; i += 256) bsum[i] = sb[i];
}

__global__ __launch_bounds__(256) void scan_pass3(
    const int* __restrict__ cnt, const int* __restrict__ bsum,
    int* __restrict__ off, int* __restrict__ cur, int N)
{
    __shared__ int part[256];
    const int t = threadIdx.x;
    const int base = blockIdx.x * 1024 + t * 4;
    int pv[4]; int s = 0;
#pragma unroll
    for (int j = 0; j < 4; ++j) {
        int idx = base + j;
        int v = (idx < N) ? cnt[idx] : 0;
        pv[j] = v + (v & 1);
        s += pv[j];
    }
    part[t] = s;
    __syncthreads();
    for (int d = 1; d < 256; d <<= 1) {
        int x = (t >= d) ? part[t - d] : 0;
        __syncthreads();
        part[t] += x;
        __syncthreads();
    }
    int run = bsum[blockIdx.x] + part[t] - s;
#pragma unroll
    for (int j = 0; j < 4; ++j) {
        int idx = base + j;
        if (idx < N) { off[idx] = run; cur[idx] = run; }
        run += pv[j];
    }
}

__global__ void scatter_kernel(const int* __restrict__ ei, int* __restrict__ cur,
                               int* __restrict__ eids, int E)
{
    int i = blockIdx.x * blockDim.x + threadIdx.x;
    const int st = gridDim.x * blockDim.x;
    for (; i < E; i += st) {
        int pos = atomicAdd(&cur[ei[E + i]], 1);
        eids[pos] = i;
    }
}

// sat[slot] = {src_as_float, att}; attr16[slot][16] = f16 edge_attr row.
// Padding slots (eid<0): sat={0,0}, attr16=0.
__global__ void permute_all(
    const int* __restrict__ ei, const float* __restrict__ eatten,
    const float* __restrict__ eattr, const int* __restrict__ eids,
    const int* __restrict__ offN,
    float2* __restrict__ sat, _Float16* __restrict__ attr16, int Scap)
{
    const int S = *offN;
    int i = blockIdx.x * blockDim.x + threadIdx.x;
    const int st = gridDim.x * blockDim.x;
    for (; i < S; i += st) {
        const int eid = eids[i];
        float2 v;
        f16x8 a0 = {}, a1 = {};
        if (eid >= 0) {
            v.x = __int_as_float(ei[eid]); v.y = eatten[eid];
            const float4* ep = (const float4*)(eattr + (size_t)eid * 16);
            float4 e0 = ep[0], e1 = ep[1], e2 = ep[2], e3 = ep[3];
            a0 = (f16x8){(_Float16)e0.x, (_Float16)e0.y, (_Float16)e0.z, (_Float16)e0.w,
                         (_Float16)e1.x, (_Float16)e1.y, (_Float16)e1.z, (_Float16)e1.w};
            a1 = (f16x8){(_Float16)e2.x, (_Float16)e2.y, (_Float16)e2.z, (_Float16)e2.w,
                         (_Float16)e3.x, (_Float16)e3.y, (_Float16)e3.z, (_Float16)e3.w};
        } else {
            v.x = __int_as_float(0); v.y = 0.f;
        }
        sat[i] = v;
        ((f16x8*)attr16)[2 * i]     = a0;
        ((f16x8*)attr16)[2 * i + 1] = a1;
    }
}

// zero the margin slots past S so MFMA tail over-reads are clean
__global__ void zero_margin(const int* __restrict__ offN,
                            float2* __restrict__ sat, _Float16* __restrict__ attr16,
                            int Scap_m)
{
    const int S = *offN;
    int i = S + (int)(blockIdx.x * blockDim.x + threadIdx.x);
    if (i < Scap_m) {
        sat[i] = make_float2(__int_as_float(0), 0.f);
        ((f16x8*)attr16)[2 * i]     = (f16x8){};
        ((f16x8*)attr16)[2 * i + 1] = (f16x8){};
    }
}

// ---------------------------------------------------------------------------
// prepack W1/W2/W_enc into MFMA B-fragment order (f16).
// ---------------------------------------------------------------------------
__global__ void prepack_w(const float* __restrict__ W1, const float* __restrict__ W2,
                          const float* __restrict__ Wenc,
                          _Float16* __restrict__ Wpk, int L)
{
    int tid = blockIdx.x * blockDim.x + threadIdx.x;
    const int total = (2 * L + 1) * 32 * 64;
    if (tid >= total) return;
    const int lane = tid & 63;
    const int f = (tid >> 6) & 31;
    const int lm = tid >> 11;
    const int kb = f >> 3, tc = f & 7;
    const float* src = (lm < L) ? (W1 + (size_t)lm * 16384)
                    : (lm < 2 * L) ? (W2 + (size_t)(lm - L) * 16384)
                    : Wenc;
    _Float16* dst = Wpk + ((size_t)lm * 32 + f) * 512 + lane * 8;
#pragma unroll
    for (int i = 0; i < 8; ++i) {
        const int k = kb * 32 + (lane >> 4) * 8 + i;
        const int col = tc * 16 + (lane & 15);
        dst[i] = (_Float16)src[k * 128 + col];
    }
}

// f32 -> f16 bulk convert (8 elems/thread)
__global__ void cvt_f16(const float* __restrict__ x, _Float16* __restrict__ y, int n8)
{
    int i = blockIdx.x * blockDim.x + threadIdx.x;
    const int st = gridDim.x * blockDim.x;
    for (; i < n8; i += st) {
        float4 a = ((const float4*)x)[2 * i];
        float4 b = ((const float4*)x)[2 * i + 1];
        f16x8 v = {(_Float16)a.x, (_Float16)a.y, (_Float16)a.z, (_Float16)a.w,
                   (_Float16)b.x, (_Float16)b.y, (_Float16)b.z, (_Float16)b.w};
        ((f16x8*)y)[i] = v;
    }
}

// ---------------------------------------------------------------------------
// Encoder MFMA: h16 = x16 @ W_enc + b_enc.
// ---------------------------------------------------------------------------
__global__ __launch_bounds__(256) void enc_mfma(
    const _Float16* __restrict__ x16, const _Float16* __restrict__ Wpk,
    const float* __restrict__ bias, _Float16* __restrict__ h16, int n)
{
    const int t = threadIdx.x;
    const int lane = t & 63;
    const int w = t >> 6;
    const int row0 = blockIdx.x * 64;
    const int lr = lane & 15;
    const int lg = lane >> 4;

    f32x4 acc[8];
#pragma unroll
    for (int tc = 0; tc < 8; ++tc) acc[tc] = (f32x4){0.f, 0.f, 0.f, 0.f};
    const int arow = min(row0 + w * 16 + lr, n - 1);
#pragma unroll
    for (int kb = 0; kb < 4; ++kb) {
        f16x8 a = *(const f16x8*)&x16[(size_t)arow * 128 + kb * 32 + lg * 8];
#pragma unroll
        for (int tc = 0; tc < 8; ++tc) {
            f16x8 b = *(const f16x8*)&Wpk[((kb * 8 + tc) * 64 + lane) * 8];
            acc[tc] = __builtin_amdgcn_mfma_f32_16x16x32_f16(a, b, acc[tc], 0, 0, 0);
        }
    }
#pragma unroll
    for (int tc = 0; tc < 8; ++tc) {
        const int col = tc * 16 + lr;
        const float bb = bias[col];
#pragma unroll
        for (int j = 0; j < 4; ++j) {
            const int row = row0 + w * 16 + lg * 4 + j;
            if (row < n)
                h16[(size_t)row * 128 + col] = (_Float16)(acc[tc][j] + bb);
        }
    }
}

// ---------------------------------------------------------------------------
// Aggregation with MFMA-computed ea: one wave per node, lane owns 2 cols.
// Per 16-slot batch: A = attr16 rows (K=32, zero-padded past 16),
// B = W_ee fragments (in regs), 8 MFMAs -> ea[16][128] -> per-wave LDS,
// then per-edge: relu(h16[src] + ea + b_ee) * att accumulated.
// ---------------------------------------------------------------------------
__global__ __launch_bounds__(256) void agg_mfma(
    const _Float16* __restrict__ h16, const float2* __restrict__ sat,
    const _Float16* __restrict__ attr16, const int* __restrict__ off,
    const float* __restrict__ W_ee, const float* __restrict__ b_ee,
    _Float16* __restrict__ z16, const float* __restrict__ eps, int layer, int N)
{
    __shared__ float eaL[4][16][132];   // per-wave tile; stride 132 -> 2-way banks
    const int t = threadIdx.x;
    const int lane = t & 63;
    const int w = t >> 6;
    const int lr = lane & 15;
    const int lg = lane >> 4;
    const int c = lane * 2;

    // B fragments of W_ee: col = tc*16+lr, k = lg*8+i (real for k<16, else 0)
    f16x8 bfrag[8];
#pragma unroll
    for (int tc = 0; tc < 8; ++tc) {
        f16x8 b = {};
        if (lg < 2) {
#pragma unroll
            for (int i = 0; i < 8; ++i) {
                const int k = lg * 8 + i;
                b[i] = (_Float16)W_ee[k * 128 + tc * 16 + lr];
            }
        }
        bfrag[tc] = b;
    }
    const float2 bv = *(const float2*)&b_ee[c];

    const int v = blockIdx.x * 4 + w;
    if (v >= N) return;
    const int e0 = off[v], e1 = off[v + 1];   // even-aligned, even length
    float a0 = 0.f, a1 = 0.f;

    for (int eb = e0; eb < e1; eb += 16) {
        // A fragment: rows = slots eb..eb+15 (tail over-reads zeroed margin)
        f16x8 af = {};
        if (lg < 2)
            af = *(const f16x8*)&attr16[(size_t)(eb + lr) * 16 + lg * 8];
#pragma unroll
        for (int tc = 0; tc < 8; ++tc) {
            f32x4 acc = __builtin_amdgcn_mfma_f32_16x16x32_f16(
                af, bfrag[tc], (f32x4){0.f, 0.f, 0.f, 0.f}, 0, 0, 0);
#pragma unroll
            for (int j = 0; j < 4; ++j)
                eaL[w][lg * 4 + j][tc * 16 + lr] = acc[j];
        }
        const int ne = min(16, e1 - eb);
        for (int u = 0; u < ne; u += 2) {
            float4 sa = *(const float4*)&sat[eb + u];   // 2 edges
            float2 ea0 = *(const float2*)&eaL[w][u][c];
            float2 ea1 = *(const float2*)&eaL[w][u + 1][c];
            uint32_t hv0 = *(const uint32_t*)&h16[(size_t)__float_as_int(sa.x) * 128 + c];
            uint32_t hv1 = *(const uint32_t*)&h16[(size_t)__float_as_int(sa.z) * 128 + c];
            __half2 hh0 = *reinterpret_cast<const __half2*>(&hv0);
            __half2 hh1 = *reinterpret_cast<const __half2*>(&hv1);
            a0 += fmaxf(__half2float(__low2half(hh0))  + ea0.x + bv.x, 0.f) * sa.y;
            a1 += fmaxf(__half2float(__high2half(hh0)) + ea0.y + bv.y, 0.f) * sa.y;
            a0 += fmaxf(__half2float(__low2half(hh1))  + ea1.x + bv.x, 0.f) * sa.w;
            a1 += fmaxf(__half2float(__high2half(hh1)) + ea1.y + bv.y, 0.f) * sa.w;
        }
    }

    const float sc = 1.0f + eps[layer];
    uint32_t hvv = *(const uint32_t*)&h16[(size_t)v * 128 + c];
    __half2 hh = *reinterpret_cast<const __half2*>(&hvv);
    float zx = fmaf(sc, __half2float(__low2half(hh)), a0);
    float zy = fmaf(sc, __half2float(__high2half(hh)), a1);
    __half2 zz = __floats2half2_rn(zx, zy);
    *reinterpret_cast<__half2*>(&z16[(size_t)v * 128 + c]) = zz;
}

// ---------------------------------------------------------------------------
// MFMA MLP: out = relu( relu(BN(z16@W1+b1)) @ W2 + b2 ).
// last==0: write h16 (f16); last==1: write f32 H.
// ---------------------------------------------------------------------------
__global__ __launch_bounds__(256) void mlp_mfma(
    const _Float16* __restrict__ z16,
    const _Float16* __restrict__ W1pk, const float* __restrict__ b1,
    const float* __restrict__ gam, const float* __restrict__ bet,
    const float* __restrict__ mu, const float* __restrict__ var,
    const _Float16* __restrict__ W2pk, const float* __restrict__ b2,
    _Float16* __restrict__ h16out, float* __restrict__ H, int last, int n)
{
    __shared__ _Float16 Yt[64][136];   // padded: 2-way banks
    const int t = threadIdx.x;
    const int lane = t & 63;
    const int w = t >> 6;
    const int row0 = blockIdx.x * 64;
    const int lr = lane & 15;
    const int lg = lane >> 4;

    f32x4 acc[8];
#pragma unroll
    for (int tc = 0; tc < 8; ++tc) acc[tc] = (f32x4){0.f, 0.f, 0.f, 0.f};
    const int arow = min(row0 + w * 16 + lr, n - 1);
#pragma unroll
    for (int kb = 0; kb < 4; ++kb) {
        f16x8 a = *(const f16x8*)&z16[(size_t)arow * 128 + kb * 32 + lg * 8];
#pragma unroll
        for (int tc = 0; tc < 8; ++tc) {
            f16x8 b = *(const f16x8*)&W1pk[((kb * 8 + tc) * 64 + lane) * 8];
            acc[tc] = __builtin_amdgcn_mfma_f32_16x16x32_f16(a, b, acc[tc], 0, 0, 0);
        }
    }
#pragma unroll
    for (int tc = 0; tc < 8; ++tc) {
        const int col = tc * 16 + lr;
        const float s  = gam[col] * rsqrtf(var[col] + 1e-5f);
        const float sh = bet[col] - mu[col] * s;
        const float bb = b1[col];
#pragma unroll
        for (int j = 0; j < 4; ++j) {
            float y = fmaxf(fmaf(acc[tc][j] + bb, s, sh), 0.f);
            Yt[w * 16 + lg * 4 + j][col] = (_Float16)y;
        }
    }
    __syncthreads();

#pragma unroll
    for (int tc = 0; tc < 8; ++tc) acc[tc] = (f32x4){0.f, 0.f, 0.f, 0.f};
#pragma unroll
    for (int kb = 0; kb < 4; ++kb) {
        f16x8 a = *(const f16x8*)&Yt[w * 16 + lr][kb * 32 + lg * 8];
#pragma unroll
        for (int tc = 0; tc < 8; ++tc) {
            f16x8 b = *(const f16x8*)&W2pk[((kb * 8 + tc) * 64 + lane) * 8];
            acc[tc] = __builtin_amdgcn_mfma_f32_16x16x32_f16(a, b, acc[tc], 0, 0, 0);
        }
    }
#pragma unroll
    for (int tc = 0; tc < 8; ++tc) {
        const int col = tc * 16 + lr;
        const float bb = b2[col];
#pragma unroll
        for (int j = 0; j < 4; ++j) {
            const int row = row0 + w * 16 + lg * 4 + j;
            if (row < n) {
                const float o = fmaxf(acc[tc][j] + bb, 0.f);
                if (last) H[(size_t)row * 128 + col] = o;
                else      h16out[(size_t)row * 128 + col] = (_Float16)o;
            }
        }
    }
}

// ---------------------------------------------------------------------------
// Fallback tier (f32 end-to-end): gemm_enc + scale_init + atomic + gemm_mlp
// ---------------------------------------------------------------------------
__global__ __launch_bounds__(512, 4) void gemm_enc(
    const float* __restrict__ A, const float* __restrict__ W,
    const float* __restrict__ bias, float* __restrict__ H, int n)
{
    __shared__ float At[64][128];
    __shared__ float Wb[2][16][128];
    const int t = threadIdx.x;
    const int tx = t & 31, ty = t >> 5;

    const int row0 = blockIdx.x * 64;
    const int nrows = min(64, n - row0);
    const int lim = nrows * 32;
    const float4* A4 = (const float4*)(A + (size_t)row0 * 128);
    float4* At4 = (float4*)&At[0][0];
#pragma unroll
    for (int i = 0; i < 4; ++i) {
        int idx = t + 512 * i;
        if (idx < lim) At4[idx] = A4[idx];
    }
    const float4* W4 = (const float4*)W;
    ((float4*)&Wb[0][0][0])[t] = W4[t];
    __syncthreads();

    float acc[4][4] = {};
    for (int c = 0; c < 8; ++c) {
        const int buf = c & 1;
        float4 wnext;
        if (c < 7) wnext = W4[(c + 1) * 512 + t];
#pragma unroll
        for (int g = 0; g < 4; ++g) {
            float4 w4[4];
#pragma unroll
            for (int kk = 0; kk < 4; ++kk) w4[kk] = *(const float4*)&Wb[buf][g * 4 + kk][tx * 4];
#pragma unroll
            for (int r = 0; r < 4; ++r) {
                float4 a = *(const float4*)&At[ty * 4 + r][c * 16 + g * 4];
                float ar[4] = {a.x, a.y, a.z, a.w};
#pragma unroll
                for (int kk = 0; kk < 4; ++kk) {
                    acc[r][0] = fmaf(ar[kk], w4[kk].x, acc[r][0]);
                    acc[r][1] = fmaf(ar[kk], w4[kk].y, acc[r][1]);
                    acc[r][2] = fmaf(ar[kk], w4[kk].z, acc[r][2]);
                    acc[r][3] = fmaf(ar[kk], w4[kk].w, acc[r][3]);
                }
            }
        }
        if (c < 7) ((float4*)&Wb[buf ^ 1][0][0])[t] = wnext;
        __syncthreads();
    }

    const int c0 = tx * 4;
    float bvv[4];
#pragma unroll
    for (int c = 0; c < 4; ++c) bvv[c] = bias[c0 + c];
#pragma unroll
    for (int r = 0; r < 4; ++r) {
        int row = row0 + ty * 4 + r;
        if (row < n) {
            float4 o;
            o.x = acc[r][0] + bvv[0]; o.y = acc[r][1] + bvv[1];
            o.z = acc[r][2] + bvv[2]; o.w = acc[r][3] + bvv[3];
            *(float4*)&H[(size_t)row * 128 + c0] = o;
        }
    }
}

__global__ void scale_init(const float* __restrict__ h, float* __restrict__ z,
                           const float* __restrict__ eps, int layer, int n4)
{
    const float s = 1.0f + eps[layer];
    int i = blockIdx.x * blockDim.x + threadIdx.x;
    const int stride = gridDim.x * blockDim.x;
    const float4* h4 = (const float4*)h;
    float4* z4 = (float4*)z;
    for (; i < n4; i += stride) {
        float4 v = h4[i];
        v.x *= s; v.y *= s; v.z *= s; v.w *= s;
        z4[i] = v;
    }
}

__global__ __launch_bounds__(256) void edge_atomic(
    const float* __restrict__ h, const int* __restrict__ ei,
    const float* __restrict__ eattr, const float* __restrict__ eatten,
    const float* __restrict__ W_ee, const float* __restrict__ b_ee,
    float* __restrict__ Z, int E)
{
    __shared__ float Wee[16][128];
    __shared__ float bee[128];
    const int t = threadIdx.x;
    const float4* We4 = (const float4*)W_ee;
    float4* Ws4 = (float4*)&Wee[0][0];
#pragma unroll
    for (int i = 0; i < 2; ++i) Ws4[t + 256 * i] = We4[t + 256 * i];
    if (t < 128) bee[t] = b_ee[t];
    __syncthreads();

    const int lane = t & 63;
    const int c = lane * 2;
    const long wid = (long)blockIdx.x * 4 + (t >> 6);
    const long nw = (long)gridDim.x * 4;
    for (long e = wid; e < E; e += nw) {
        const int src = ei[e];
        const int dst = ei[E + e];
        const float att = eatten[e];
        union { float4 v4[4]; float f[16]; } ea;
        const float4* eap = (const float4*)(eattr + e * 16);
        ea.v4[0] = eap[0]; ea.v4[1] = eap[1]; ea.v4[2] = eap[2]; ea.v4[3] = eap[3];
        float2 hv = *(const float2*)&h[(size_t)src * 128 + c];
        float e0 = bee[c], e1 = bee[c + 1];
#pragma unroll
        for (int k = 0; k < 16; ++k) {
            float2 w = *(const float2*)&Wee[k][c];
            e0 = fmaf(ea.f[k], w.x, e0);
            e1 = fmaf(ea.f[k], w.y, e1);
        }
        float m0 = fmaxf(hv.x + e0, 0.f) * att;
        float m1 = fmaxf(hv.y + e1, 0.f) * att;
        atomic_add2(&Z[(size_t)dst * 128 + c], m0, m1);
    }
}

__global__ __launch_bounds__(512, 4) void gemm_mlp(
    const float* __restrict__ Z,
    const float* __restrict__ W1, const float* __restrict__ b1,
    const float* __restrict__ gam, const float* __restrict__ bet,
    const float* __restrict__ mu, const float* __restrict__ var,
    const float* __restrict__ W2, const float* __restrict__ b2,
    float* __restrict__ H, int n)
{
    __shared__ float At[64][128];
    __shared__ float Wb[2][16][128];
    const int t = threadIdx.x;
    const int tx = t & 31, ty = t >> 5;

    const int row0 = blockIdx.x * 64;
    const int nrows = min(64, n - row0);
    const int lim = nrows * 32;
    const float4* Z4 = (const float4*)(Z + (size_t)row0 * 128);
    float4* At4 = (float4*)&At[0][0];
#pragma unroll
    for (int i = 0; i < 4; ++i) {
        int idx = t + 512 * i;
        if (idx < lim) At4[idx] = Z4[idx];
    }
    const float4* W14 = (const float4*)W1;
    ((float4*)&Wb[0][0][0])[t] = W14[t];
    __syncthreads();

    float acc[4][4] = {};
    for (int c = 0; c < 8; ++c) {
        const int buf = c & 1;
        float4 wnext;
        if (c < 7) wnext = W14[(c + 1) * 512 + t];
#pragma unroll
        for (int g = 0; g < 4; ++g) {
            float4 w4[4];
#pragma unroll
            for (int kk = 0; kk < 4; ++kk) w4[kk] = *(const float4*)&Wb[buf][g * 4 + kk][tx * 4];
#pragma unroll
            for (int r = 0; r < 4; ++r) {
                float4 a = *(const float4*)&At[ty * 4 + r][c * 16 + g * 4];
                float ar[4] = {a.x, a.y, a.z, a.w};
#pragma unroll
                for (int kk = 0; kk < 4; ++kk) {
                    acc[r][0] = fmaf(ar[kk], w4[kk].x, acc[r][0]);
                    acc[r][1] = fmaf(ar[kk], w4[kk].y, acc[r][1]);
                    acc[r][2] = fmaf(ar[kk], w4[kk].z, acc[r][2]);
                    acc[r][3] = fmaf(ar[kk], w4[kk].w, acc[r][3]);
                }
            }
        }
        if (c < 7) ((float4*)&Wb[buf ^ 1][0][0])[t] = wnext;
        __syncthreads();
    }

    const int c0 = tx * 4;
    const float4* W24 = (const float4*)W2;
    float4 w2pre = W24[t];
    {
        float b1v[4], scv[4], shv[4];
#pragma unroll
        for (int cl = 0; cl < 4; ++cl) {
            b1v[cl] = b1[c0 + cl];
            float s = gam[c0 + cl] * rsqrtf(var[c0 + cl] + 1e-5f);
            scv[cl] = s;
            shv[cl] = bet[c0 + cl] - mu[c0 + cl] * s;
        }
#pragma unroll
        for (int r = 0; r < 4; ++r) {
            float4 y;
            y.x = fmaxf(fmaf(acc[r][0] + b1v[0], scv[0], shv[0]), 0.f);
            y.y = fmaxf(fmaf(acc[r][1] + b1v[1], scv[1], shv[1]), 0.f);
            y.z = fmaxf(fmaf(acc[r][2] + b1v[2], scv[2], shv[2]), 0.f);
            y.w = fmaxf(fmaf(acc[r][3] + b1v[3], scv[3], shv[3]), 0.f);
            *(float4*)&At[ty * 4 + r][c0] = y;
            acc[r][0] = 0.f; acc[r][1] = 0.f; acc[r][2] = 0.f; acc[r][3] = 0.f;
        }
    }
    ((float4*)&Wb[0][0][0])[t] = w2pre;
    __syncthreads();

    for (int c = 0; c < 8; ++c) {
        const int buf = c & 1;
        float4 wnext;
        if (c < 7) wnext = W24[(c + 1) * 512 + t];
#pragma unroll
        for (int g = 0; g < 4; ++g) {
            float4 w4[4];
#pragma unroll
            for (int kk = 0; kk < 4; ++kk) w4[kk] = *(const float4*)&Wb[buf][g * 4 + kk][tx * 4];
#pragma unroll
            for (int r = 0; r < 4; ++r) {
                float4 a = *(const float4*)&At[ty * 4 + r][c * 16 + g * 4];
                float ar[4] = {a.x, a.y, a.z, a.w};
#pragma unroll
                for (int kk = 0; kk < 4; ++kk) {
                    acc[r][0] = fmaf(ar[kk], w4[kk].x, acc[r][0]);
                    acc[r][1] = fmaf(ar[kk], w4[kk].y, acc[r][1]);
                    acc[r][2] = fmaf(ar[kk], w4[kk].z, acc[r][2]);
                    acc[r][3] = fmaf(ar[kk], w4[kk].w, acc[r][3]);
                }
            }
        }
        if (c < 7) ((float4*)&Wb[buf ^ 1][0][0])[t] = wnext;
        __syncthreads();
    }

    float b2v[4];
#pragma unroll
    for (int cl = 0; cl < 4; ++cl) b2v[cl] = b2[c0 + cl];
#pragma unroll
    for (int r = 0; r < 4; ++r) {
        int row = row0 + ty * 4 + r;
        if (row < n) {
            float4 o;
            o.x = fmaxf(acc[r][0] + b2v[0], 0.f);
            o.y = fmaxf(acc[r][1] + b2v[1], 0.f);
            o.z = fmaxf(acc[r][2] + b2v[2], 0.f);
            o.w = fmaxf(acc[r][3] + b2v[3], 0.f);
            *(float4*)&H[(size_t)row * 128 + c0] = o;
        }
    }
}

extern "C" void kernel_launch(void* const* d_in, const int* in_sizes, int n_in,
                              void* d_out, int out_size, void* d_ws, size_t ws_size,
                              hipStream_t stream)
{
    const float* x      = (const float*)d_in[0];
    const int*   ei     = (const int*)d_in[1];
    // d_in[2] = batch (unused)
    const float* eattr  = (const float*)d_in[3];
    const float* eatten = (const float*)d_in[4];
    const float* W_enc  = (const float*)d_in[5];
    const float* b_enc  = (const float*)d_in[6];
    const float* W_ee   = (const float*)d_in[7];
    const float* b_ee   = (const float*)d_in[8];
    const float* eps    = (const float*)d_in[9];
    const float* W1     = (const float*)d_in[10];
    const float* b1     = (const float*)d_in[11];
    const float* gam    = (const float*)d_in[12];
    const float* bet    = (const float*)d_in[13];
    const float* mu     = (const float*)d_in[14];
    const float* var    = (const float*)d_in[15];
    const float* W2     = (const float*)d_in[16];
    const float* b2     = (const float*)d_in[17];

    const int N = in_sizes[0] / 128;
    const int E = in_sizes[1] / 2;
    const int L = in_sizes[9];
    const int Scap = E + N;          // max padded slots
    const int Scap_m = Scap + 16;    // +16 margin for MFMA tail over-read

    float* hout = (float*)d_out;   // final f32 output

    // workspace layout (main path). x16 aliases z16 (x16 dead after enc).
    char* p = (char*)d_ws;
    _Float16* z16 = (_Float16*)p;       p += ((size_t)N * 128 * 2 + 255) & ~(size_t)255;
    _Float16* h16 = (_Float16*)p;       p += ((size_t)N * 128 * 2 + 255) & ~(size_t)255;
    int* off  = (int*)p;                p += 4 * (size_t)(N + 1);
    int* cur  = (int*)p;                p += 4 * (size_t)N;
    int* cnt  = (int*)p;                p += 4 * (size_t)N;
    int* bsum = (int*)p;                p += 4 * 1024;
    int* eids = (int*)p;                p += 4 * (size_t)Scap;
    p = (char*)(((uintptr_t)p + 255) & ~(uintptr_t)255);
    float2* sat = (float2*)p;           p += 8 * (size_t)Scap_m;
    p = (char*)(((uintptr_t)p + 255) & ~(uintptr_t)255);
    _Float16* attr16 = (_Float16*)p;    p += 32 * (size_t)Scap_m;
    p = (char*)(((uintptr_t)p + 255) & ~(uintptr_t)255);
    _Float16* Wpk = (_Float16*)p;       p += (2 * (size_t)L + 1) * 32 * 512 * 2;
    const size_t need_main = (size_t)(p - (char*)d_ws);

    const bool use_main = ws_size >= need_main;
    const int tiles = (N + 63) / 64;
    const int NB = (N + 1023) / 1024;

    if (use_main) {
        _Float16* x16 = z16;   // alias: x16 dead once layer-0 agg writes z16

        init_arrays<<<1024, 256, 0, stream>>>(cnt, N, eids, Scap);
        hist_kernel<<<1024, 256, 0, stream>>>(ei, cnt, E);
        scan_pass1<<<NB, 256, 0, stream>>>(cnt, bsum, N);
        scan_pass2<<<1, 256, 0, stream>>>(bsum, off, NB, N);
        scan_pass3<<<NB, 256, 0, stream>>>(cnt, bsum, off, cur, N);
        scatter_kernel<<<1024, 256, 0, stream>>>(ei, cur, eids, E);
        permute_all<<<2048, 256, 0, stream>>>(ei, eatten, eattr, eids, off + N,
                                              sat, attr16, Scap_m);
        zero_margin<<<(N + 16 + 255) / 256, 256, 0, stream>>>(off + N, sat, attr16, Scap_m);
        prepack_w<<<((2 * L + 1) * 32 * 64 + 255) / 256, 256, 0, stream>>>(
            W1, W2, W_enc, Wpk, L);

        cvt_f16<<<2048, 256, 0, stream>>>(x, x16, N * 128 / 8);
        enc_mfma<<<tiles, 256, 0, stream>>>(
            x16, Wpk + (size_t)(2 * L) * 32 * 512, b_enc, h16, N);

        for (int i = 0; i < L; ++i) {
            agg_mfma<<<(N + 3) / 4, 256, 0, stream>>>(
                h16, sat, attr16, off, W_ee, b_ee, z16, eps, i, N);
            mlp_mfma<<<tiles, 256, 0, stream>>>(
                z16,
                Wpk + (size_t)i * 32 * 512, b1 + i * 128,
                gam + i * 128, bet + i * 128, mu + i * 128, var + i * 128,
                Wpk + (size_t)(L + i) * 32 * 512, b2 + i * 128,
                h16, hout, (i == L - 1) ? 1 : 0, N);
        }
        return;
    }

    // fallback: f32 atomic tier (zbuf at ws start)
    float* zbuf = (float*)d_ws;
    float* h = hout;
    gemm_enc<<<tiles, 512, 0, stream>>>(x, W_enc, b_enc, h, N);
    for (int i = 0; i < L; ++i) {
        scale_init<<<2048, 256, 0, stream>>>(h, zbuf, eps, i, N * 128 / 4);
        edge_atomic<<<2048, 256, 0, stream>>>(h, ei, eattr, eatten, W_ee, b_ee, zbuf, E);
        gemm_mlp<<<tiles, 512, 0, stream>>>(
            zbuf, W1 + (size_t)i * 128 * 128, b1 + i * 128,
            gam + i * 128, bet + i * 128, mu + i * 128, var + i * 128,
            W2 + (size_t)i * 128 * 128, b2 + i * 128,
            h, N);
    }
}

// Round 15
// 423.327 us; speedup vs baseline: 1.5645x; 1.5645x over previous
//
#include <hip/hip_runtime.h>
#include <hip/hip_fp16.h>
#include <cstdint>
#include <cstddef>

// ---------------------------------------------------------------------------
// GIN (GINEConv x3) forward. f32 in/out; f16 h/z; FP8(e4m3) precomputed ea.
//   x16 = f16(x); h16 = x16@W_enc + b (enc_mfma)
//   CSR (deg padded even) -> sat{src,att} + eab8 (fp8 ea, pair-interleaved)
//   per layer: agg_f8 (h16 gather + fp8 ea decode) -> z16
//              mlp_mfma (16x16x32 f16) -> h16 (last layer: f32 d_out)
// ---------------------------------------------------------------------------

typedef _Float16 f16x8 __attribute__((ext_vector_type(8)));
typedef float    f32x4 __attribute__((ext_vector_type(4)));
typedef float    f32x2 __attribute__((ext_vector_type(2)));

// ---- fp8 e4m3 pack/unpack with compile-safe fallback ----------------------
__device__ inline uint32_t pack_fp8_pair(float a, float b) {
#if __has_builtin(__builtin_amdgcn_cvt_pk_fp8_f32)
    return (uint32_t)__builtin_amdgcn_cvt_pk_fp8_f32(a, b, 0, false) & 0xFFFFu;
#else
    auto enc = [](float x) -> uint32_t {
        uint32_t s = (x < 0.f) ? 0x80u : 0u;
        float ax = fabsf(x);
        if (!(ax >= 1.953125e-3f)) {             // subnormal / zero
            int mi = (int)(ax * 512.f + 0.5f);
            if (mi > 7) mi = 7;
            return s | (uint32_t)mi;
        }
        ax = fminf(ax, 448.f);
        int e; float m = frexpf(ax, &e);         // ax = m * 2^e, m in [0.5,1)
        int E = e - 1 + 7;
        int mi = (int)((m * 2.f - 1.f) * 8.f + 0.5f);
        if (mi == 8) { mi = 0; ++E; }
        if (E > 15 || (E == 15 && mi == 7)) { E = 15; mi = 6; }
        return s | ((uint32_t)E << 3) | (uint32_t)mi;
    };
    return enc(a) | (enc(b) << 8);
#endif
}

template <bool HIGH>
__device__ inline f32x2 unpack_fp8_pair(uint32_t w) {
#if __has_builtin(__builtin_amdgcn_cvt_pk_f32_fp8)
    return __builtin_amdgcn_cvt_pk_f32_fp8((int)w, HIGH);
#else
    auto dec = [](uint32_t v) -> float {
        uint32_t s = v >> 7, e = (v >> 3) & 0xF, m = v & 7;
        float r = (e == 0) ? ldexpf((float)m, -9)
                           : ldexpf(1.f + (float)m / 8.f, (int)e - 7);
        return s ? -r : r;
    };
    uint32_t b0 = HIGH ? ((w >> 16) & 0xFF) : (w & 0xFF);
    uint32_t b1 = HIGH ? ((w >> 24) & 0xFF) : ((w >> 8) & 0xFF);
    return (f32x2){dec(b0), dec(b1)};
#endif
}

// ---- packed-f32x2 atomic with compile-safe fallback (fallback tier only) ---
template <class T>
__device__ inline auto add2_impl(T* p, T v, int)
    -> decltype(unsafeAtomicAdd(p, v), void()) {
    unsafeAtomicAdd(p, v);
}
template <class T>
__device__ inline void add2_impl(T* p, T v, long) {
    unsafeAtomicAdd(&p->x, v.x);
    unsafeAtomicAdd(&p->y, v.y);
}
__device__ inline void atomic_add2(float* p, float x, float y) {
    add2_impl(reinterpret_cast<float2*>(p), make_float2(x, y), 0);
}

// ---------------------------------------------------------------------------
// CSR build
// ---------------------------------------------------------------------------
__global__ void init_arrays(int* __restrict__ cnt, int N, int* __restrict__ eids, int S)
{
    int i = blockIdx.x * blockDim.x + threadIdx.x;
    const int st = gridDim.x * blockDim.x;
    for (int j = i; j < N; j += st) cnt[j] = 0;
    for (int j = i; j < S; j += st) eids[j] = -1;
}

__global__ void hist_kernel(const int* __restrict__ ei, int* __restrict__ cnt, int E)
{
    int i = blockIdx.x * blockDim.x + threadIdx.x;
    const int st = gridDim.x * blockDim.x;
    for (; i < E; i += st) atomicAdd(&cnt[ei[E + i]], 1);
}

__global__ __launch_bounds__(256) void scan_pass1(
    const int* __restrict__ cnt, int* __restrict__ bsum, int N)
{
    __shared__ int part[256];
    const int t = threadIdx.x;
    const int base = blockIdx.x * 1024 + t * 4;
    int s = 0;
#pragma unroll
    for (int j = 0; j < 4; ++j) {
        int idx = base + j;
        if (idx < N) { int v = cnt[idx]; s += v + (v & 1); }
    }
    part[t] = s;
    __syncthreads();
    for (int d = 128; d > 0; d >>= 1) {
        if (t < d) part[t] += part[t + d];
        __syncthreads();
    }
    if (t == 0) bsum[blockIdx.x] = part[0];
}

__global__ __launch_bounds__(256) void scan_pass2(
    int* __restrict__ bsum, int* __restrict__ off, int NB, int N)
{
    __shared__ int sb[1024];
    const int t = threadIdx.x;
    for (int i = t; i < NB; i += 256) sb[i] = bsum[i];
    __syncthreads();
    if (t == 0) {
        int run = 0;
        for (int i = 0; i < NB; ++i) { int v = sb[i]; sb[i] = run; run += v; }
        off[N] = run;          // total padded slots S
    }
    __syncthreads();
    for (int i = t; i < NB; i += 256) bsum[i] = sb[i];
}

__global__ __launch_bounds__(256) void scan_pass3(
    const int* __restrict__ cnt, const int* __restrict__ bsum,
    int* __restrict__ off, int* __restrict__ cur, int N)
{
    __shared__ int part[256];
    const int t = threadIdx.x;
    const int base = blockIdx.x * 1024 + t * 4;
    int pv[4]; int s = 0;
#pragma unroll
    for (int j = 0; j < 4; ++j) {
        int idx = base + j;
        int v = (idx < N) ? cnt[idx] : 0;
        pv[j] = v + (v & 1);
        s += pv[j];
    }
    part[t] = s;
    __syncthreads();
    for (int d = 1; d < 256; d <<= 1) {
        int x = (t >= d) ? part[t - d] : 0;
        __syncthreads();
        part[t] += x;
        __syncthreads();
    }
    int run = bsum[blockIdx.x] + part[t] - s;
#pragma unroll
    for (int j = 0; j < 4; ++j) {
        int idx = base + j;
        if (idx < N) { off[idx] = run; cur[idx] = run; }
        run += pv[j];
    }
}

__global__ void scatter_kernel(const int* __restrict__ ei, int* __restrict__ cur,
                               int* __restrict__ eids, int E)
{
    int i = blockIdx.x * blockDim.x + threadIdx.x;
    const int st = gridDim.x * blockDim.x;
    for (; i < E; i += st) {
        int pos = atomicAdd(&cur[ei[E + i]], 1);
        eids[pos] = i;
    }
}

// sat[slot] = {src_as_float, att}; padding slots (eid<0) -> {0, 0}
__global__ void permute_sat(
    const int* __restrict__ ei, const float* __restrict__ eatten,
    const int* __restrict__ eids, const int* __restrict__ offN,
    float2* __restrict__ sat, int Scap)
{
    const int S = *offN;
    int i = blockIdx.x * blockDim.x + threadIdx.x;
    const int st = gridDim.x * blockDim.x;
    for (; i < S; i += st) {
        const int eid = eids[i];
        float2 v;
        if (eid >= 0) { v.x = __int_as_float(ei[eid]); v.y = eatten[eid]; }
        else          { v.x = __int_as_float(0);       v.y = 0.f; }
        sat[i] = v;
    }
}

// ---------------------------------------------------------------------------
// eabuild: ea = edge_attr@W_ee + b_ee, FP8 e4m3, PAIR-INTERLEAVED layout:
//   u16 at  ((slot>>1)*128 + lane*2 + (slot&1))  (u16 units)
//   -> per pair 256 B; lane's dword = {ev.c, ev.c+1, od.c, od.c+1}
// ---------------------------------------------------------------------------
__global__ __launch_bounds__(256) void eabuild_staged(
    const int* __restrict__ eids, const float* __restrict__ eattr,
    const float* __restrict__ W_ee, const float* __restrict__ b_ee,
    const int* __restrict__ offN, uint16_t* __restrict__ eab8, int Scap)
{
    __shared__ int   se[256];
    __shared__ float sattr[256 * 16];
    const int t = threadIdx.x;
    const int lane = t & 63;
    const int wv = t >> 6;
    const int c = lane * 2;

    const int S = *offN;
    const int base = blockIdx.x * 256;
    const int n = min(256, S - base);
    if (n <= 0) return;

    float2 w[16];
#pragma unroll
    for (int k = 0; k < 16; ++k) w[k] = *(const float2*)&W_ee[k * 128 + c];
    const float2 bv = *(const float2*)&b_ee[c];

    if (t < n) se[t] = eids[base + t];
    __syncthreads();

    float4* sa4 = (float4*)sattr;
    const float4* ea4 = (const float4*)eattr;
    for (int i = t; i < n * 4; i += 256) {
        const int row = i >> 2, part = i & 3;
        const int eid = se[row];
        sa4[i] = (eid >= 0) ? ea4[(size_t)eid * 4 + part]
                            : make_float4(0.f, 0.f, 0.f, 0.f);
    }
    __syncthreads();

    for (int slot = wv; slot < n; slot += 4) {
        const int gs = base + slot;
        uint32_t out = 0;
        if (se[slot] >= 0) {
            const float4* sr = (const float4*)&sattr[slot * 16];
            float4 e0 = sr[0], e1 = sr[1], e2 = sr[2], e3 = sr[3];
            const float ef[16] = {e0.x, e0.y, e0.z, e0.w, e1.x, e1.y, e1.z, e1.w,
                                  e2.x, e2.y, e2.z, e2.w, e3.x, e3.y, e3.z, e3.w};
            float d0 = bv.x, d1 = bv.y;
#pragma unroll
            for (int k = 0; k < 16; ++k) {
                d0 = fmaf(ef[k], w[k].x, d0);
                d1 = fmaf(ef[k], w[k].y, d1);
            }
            out = pack_fp8_pair(d0, d1);
        }
        eab8[(size_t)(gs >> 1) * 128 + lane * 2 + (gs & 1)] = (uint16_t)out;
    }
}

// ---------------------------------------------------------------------------
// prepack W1/W2/W_enc into MFMA B-fragment order (f16).
// ---------------------------------------------------------------------------
__global__ void prepack_w(const float* __restrict__ W1, const float* __restrict__ W2,
                          const float* __restrict__ Wenc,
                          _Float16* __restrict__ Wpk, int L)
{
    int tid = blockIdx.x * blockDim.x + threadIdx.x;
    const int total = (2 * L + 1) * 32 * 64;
    if (tid >= total) return;
    const int lane = tid & 63;
    const int f = (tid >> 6) & 31;
    const int lm = tid >> 11;
    const int kb = f >> 3, tc = f & 7;
    const float* src = (lm < L) ? (W1 + (size_t)lm * 16384)
                    : (lm < 2 * L) ? (W2 + (size_t)(lm - L) * 16384)
                    : Wenc;
    _Float16* dst = Wpk + ((size_t)lm * 32 + f) * 512 + lane * 8;
#pragma unroll
    for (int i = 0; i < 8; ++i) {
        const int k = kb * 32 + (lane >> 4) * 8 + i;
        const int col = tc * 16 + (lane & 15);
        dst[i] = (_Float16)src[k * 128 + col];
    }
}

// f32 -> f16 bulk convert (8 elems/thread)
__global__ void cvt_f16(const float* __restrict__ x, _Float16* __restrict__ y, int n8)
{
    int i = blockIdx.x * blockDim.x + threadIdx.x;
    const int st = gridDim.x * blockDim.x;
    for (; i < n8; i += st) {
        float4 a = ((const float4*)x)[2 * i];
        float4 b = ((const float4*)x)[2 * i + 1];
        f16x8 v = {(_Float16)a.x, (_Float16)a.y, (_Float16)a.z, (_Float16)a.w,
                   (_Float16)b.x, (_Float16)b.y, (_Float16)b.z, (_Float16)b.w};
        ((f16x8*)y)[i] = v;
    }
}

// ---------------------------------------------------------------------------
// Encoder MFMA: h16 = x16 @ W_enc + b_enc.
// ---------------------------------------------------------------------------
__global__ __launch_bounds__(256) void enc_mfma(
    const _Float16* __restrict__ x16, const _Float16* __restrict__ Wpk,
    const float* __restrict__ bias, _Float16* __restrict__ h16, int n)
{
    const int t = threadIdx.x;
    const int lane = t & 63;
    const int w = t >> 6;
    const int row0 = blockIdx.x * 64;
    const int lr = lane & 15;
    const int lg = lane >> 4;

    f32x4 acc[8];
#pragma unroll
    for (int tc = 0; tc < 8; ++tc) acc[tc] = (f32x4){0.f, 0.f, 0.f, 0.f};
    const int arow = min(row0 + w * 16 + lr, n - 1);
#pragma unroll
    for (int kb = 0; kb < 4; ++kb) {
        f16x8 a = *(const f16x8*)&x16[(size_t)arow * 128 + kb * 32 + lg * 8];
#pragma unroll
        for (int tc = 0; tc < 8; ++tc) {
            f16x8 b = *(const f16x8*)&Wpk[((kb * 8 + tc) * 64 + lane) * 8];
            acc[tc] = __builtin_amdgcn_mfma_f32_16x16x32_f16(a, b, acc[tc], 0, 0, 0);
        }
    }
#pragma unroll
    for (int tc = 0; tc < 8; ++tc) {
        const int col = tc * 16 + lr;
        const float bb = bias[col];
#pragma unroll
        for (int j = 0; j < 4; ++j) {
            const int row = row0 + w * 16 + lg * 4 + j;
            if (row < n)
                h16[(size_t)row * 128 + col] = (_Float16)(acc[tc][j] + bb);
        }
    }
}

// ---------------------------------------------------------------------------
// Aggregation: one wave per node, lane owns 2 cols. h16 gather + fp8 ea.
// ---------------------------------------------------------------------------
__global__ __launch_bounds__(256) void agg_f8(
    const _Float16* __restrict__ h16, const float2* __restrict__ sat,
    const uint32_t* __restrict__ eab8, const int* __restrict__ off,
    _Float16* __restrict__ z16, const float* __restrict__ eps, int layer, int N)
{
    const int t = threadIdx.x;
    const int v = blockIdx.x * 4 + (t >> 6);
    if (v >= N) return;
    const int lane = t & 63;
    const int c = lane * 2;

    const int e0 = off[v], e1 = off[v + 1];   // even-aligned, even length
    float a0 = 0.f, a1 = 0.f;
    int e = e0;
    for (; e + 8 <= e1; e += 8) {
        float4 sa[2];
        sa[0] = *(const float4*)&sat[e];
        sa[1] = *(const float4*)&sat[e + 2];
        float4 sb[2];
        sb[0] = *(const float4*)&sat[e + 4];
        sb[1] = *(const float4*)&sat[e + 6];
        uint32_t eb[4];
#pragma unroll
        for (int j = 0; j < 4; ++j)
            eb[j] = eab8[(size_t)((e >> 1) + j) * 64 + lane];
        uint32_t hv[8];
        hv[0] = *(const uint32_t*)&h16[(size_t)__float_as_int(sa[0].x) * 128 + c];
        hv[1] = *(const uint32_t*)&h16[(size_t)__float_as_int(sa[0].z) * 128 + c];
        hv[2] = *(const uint32_t*)&h16[(size_t)__float_as_int(sa[1].x) * 128 + c];
        hv[3] = *(const uint32_t*)&h16[(size_t)__float_as_int(sa[1].z) * 128 + c];
        hv[4] = *(const uint32_t*)&h16[(size_t)__float_as_int(sb[0].x) * 128 + c];
        hv[5] = *(const uint32_t*)&h16[(size_t)__float_as_int(sb[0].z) * 128 + c];
        hv[6] = *(const uint32_t*)&h16[(size_t)__float_as_int(sb[1].x) * 128 + c];
        hv[7] = *(const uint32_t*)&h16[(size_t)__float_as_int(sb[1].z) * 128 + c];
#pragma unroll
        for (int j = 0; j < 4; ++j) {
            const float4 s4 = (j < 2) ? sa[j] : sb[j - 2];
            f32x2 ev = unpack_fp8_pair<false>(eb[j]);
            f32x2 od = unpack_fp8_pair<true>(eb[j]);
            __half2 h0 = *reinterpret_cast<const __half2*>(&hv[2 * j]);
            __half2 h1 = *reinterpret_cast<const __half2*>(&hv[2 * j + 1]);
            a0 += fmaxf(__half2float(__low2half(h0))  + ev[0], 0.f) * s4.y;
            a1 += fmaxf(__half2float(__high2half(h0)) + ev[1], 0.f) * s4.y;
            a0 += fmaxf(__half2float(__low2half(h1))  + od[0], 0.f) * s4.w;
            a1 += fmaxf(__half2float(__high2half(h1)) + od[1], 0.f) * s4.w;
        }
    }
    for (; e < e1; e += 2) {
        float4 sa = *(const float4*)&sat[e];
        uint32_t eb = eab8[(size_t)(e >> 1) * 64 + lane];
        uint32_t hv0 = *(const uint32_t*)&h16[(size_t)__float_as_int(sa.x) * 128 + c];
        uint32_t hv1 = *(const uint32_t*)&h16[(size_t)__float_as_int(sa.z) * 128 + c];
        f32x2 ev = unpack_fp8_pair<false>(eb);
        f32x2 od = unpack_fp8_pair<true>(eb);
        __half2 h0 = *reinterpret_cast<const __half2*>(&hv0);
        __half2 h1 = *reinterpret_cast<const __half2*>(&hv1);
        a0 += fmaxf(__half2float(__low2half(h0))  + ev[0], 0.f) * sa.y;
        a1 += fmaxf(__half2float(__high2half(h0)) + ev[1], 0.f) * sa.y;
        a0 += fmaxf(__half2float(__low2half(h1))  + od[0], 0.f) * sa.w;
        a1 += fmaxf(__half2float(__high2half(h1)) + od[1], 0.f) * sa.w;
    }

    const float sc = 1.0f + eps[layer];
    uint32_t hvv = *(const uint32_t*)&h16[(size_t)v * 128 + c];
    __half2 hh = *reinterpret_cast<const __half2*>(&hvv);
    float zx = fmaf(sc, __half2float(__low2half(hh)), a0);
    float zy = fmaf(sc, __half2float(__high2half(hh)), a1);
    __half2 zz = __floats2half2_rn(zx, zy);
    *reinterpret_cast<__half2*>(&z16[(size_t)v * 128 + c]) = zz;
}

// ---------------------------------------------------------------------------
// MFMA MLP: out = relu( relu(BN(z16@W1+b1)) @ W2 + b2 ).
// last==0: write h16 (f16); last==1: write f32 H.
// ---------------------------------------------------------------------------
__global__ __launch_bounds__(256) void mlp_mfma(
    const _Float16* __restrict__ z16,
    const _Float16* __restrict__ W1pk, const float* __restrict__ b1,
    const float* __restrict__ gam, const float* __restrict__ bet,
    const float* __restrict__ mu, const float* __restrict__ var,
    const _Float16* __restrict__ W2pk, const float* __restrict__ b2,
    _Float16* __restrict__ h16out, float* __restrict__ H, int last, int n)
{
    __shared__ _Float16 Yt[64][136];   // padded: 2-way banks
    const int t = threadIdx.x;
    const int lane = t & 63;
    const int w = t >> 6;
    const int row0 = blockIdx.x * 64;
    const int lr = lane & 15;
    const int lg = lane >> 4;

    f32x4 acc[8];
#pragma unroll
    for (int tc = 0; tc < 8; ++tc) acc[tc] = (f32x4){0.f, 0.f, 0.f, 0.f};
    const int arow = min(row0 + w * 16 + lr, n - 1);
#pragma unroll
    for (int kb = 0; kb < 4; ++kb) {
        f16x8 a = *(const f16x8*)&z16[(size_t)arow * 128 + kb * 32 + lg * 8];
#pragma unroll
        for (int tc = 0; tc < 8; ++tc) {
            f16x8 b = *(const f16x8*)&W1pk[((kb * 8 + tc) * 64 + lane) * 8];
            acc[tc] = __builtin_amdgcn_mfma_f32_16x16x32_f16(a, b, acc[tc], 0, 0, 0);
        }
    }
#pragma unroll
    for (int tc = 0; tc < 8; ++tc) {
        const int col = tc * 16 + lr;
        const float s  = gam[col] * rsqrtf(var[col] + 1e-5f);
        const float sh = bet[col] - mu[col] * s;
        const float bb = b1[col];
#pragma unroll
        for (int j = 0; j < 4; ++j) {
            float y = fmaxf(fmaf(acc[tc][j] + bb, s, sh), 0.f);
            Yt[w * 16 + lg * 4 + j][col] = (_Float16)y;
        }
    }
    __syncthreads();

#pragma unroll
    for (int tc = 0; tc < 8; ++tc) acc[tc] = (f32x4){0.f, 0.f, 0.f, 0.f};
#pragma unroll
    for (int kb = 0; kb < 4; ++kb) {
        f16x8 a = *(const f16x8*)&Yt[w * 16 + lr][kb * 32 + lg * 8];
#pragma unroll
        for (int tc = 0; tc < 8; ++tc) {
            f16x8 b = *(const f16x8*)&W2pk[((kb * 8 + tc) * 64 + lane) * 8];
            acc[tc] = __builtin_amdgcn_mfma_f32_16x16x32_f16(a, b, acc[tc], 0, 0, 0);
        }
    }
#pragma unroll
    for (int tc = 0; tc < 8; ++tc) {
        const int col = tc * 16 + lr;
        const float bb = b2[col];
#pragma unroll
        for (int j = 0; j < 4; ++j) {
            const int row = row0 + w * 16 + lg * 4 + j;
            if (row < n) {
                const float o = fmaxf(acc[tc][j] + bb, 0.f);
                if (last) H[(size_t)row * 128 + col] = o;
                else      h16out[(size_t)row * 128 + col] = (_Float16)o;
            }
        }
    }
}

// ---------------------------------------------------------------------------
// Fallback tier (f32 end-to-end): gemm_enc + scale_init + atomic + gemm_mlp
// ---------------------------------------------------------------------------
__global__ __launch_bounds__(512, 4) void gemm_enc(
    const float* __restrict__ A, const float* __restrict__ W,
    const float* __restrict__ bias, float* __restrict__ H, int n)
{
    __shared__ float At[64][128];
    __shared__ float Wb[2][16][128];
    const int t = threadIdx.x;
    const int tx = t & 31, ty = t >> 5;

    const int row0 = blockIdx.x * 64;
    const int nrows = min(64, n - row0);
    const int lim = nrows * 32;
    const float4* A4 = (const float4*)(A + (size_t)row0 * 128);
    float4* At4 = (float4*)&At[0][0];
#pragma unroll
    for (int i = 0; i < 4; ++i) {
        int idx = t + 512 * i;
        if (idx < lim) At4[idx] = A4[idx];
    }
    const float4* W4 = (const float4*)W;
    ((float4*)&Wb[0][0][0])[t] = W4[t];
    __syncthreads();

    float acc[4][4] = {};
    for (int c = 0; c < 8; ++c) {
        const int buf = c & 1;
        float4 wnext;
        if (c < 7) wnext = W4[(c + 1) * 512 + t];
#pragma unroll
        for (int g = 0; g < 4; ++g) {
            float4 w4[4];
#pragma unroll
            for (int kk = 0; kk < 4; ++kk) w4[kk] = *(const float4*)&Wb[buf][g * 4 + kk][tx * 4];
#pragma unroll
            for (int r = 0; r < 4; ++r) {
                float4 a = *(const float4*)&At[ty * 4 + r][c * 16 + g * 4];
                float ar[4] = {a.x, a.y, a.z, a.w};
#pragma unroll
                for (int kk = 0; kk < 4; ++kk) {
                    acc[r][0] = fmaf(ar[kk], w4[kk].x, acc[r][0]);
                    acc[r][1] = fmaf(ar[kk], w4[kk].y, acc[r][1]);
                    acc[r][2] = fmaf(ar[kk], w4[kk].z, acc[r][2]);
                    acc[r][3] = fmaf(ar[kk], w4[kk].w, acc[r][3]);
                }
            }
        }
        if (c < 7) ((float4*)&Wb[buf ^ 1][0][0])[t] = wnext;
        __syncthreads();
    }

    const int c0 = tx * 4;
    float bvv[4];
#pragma unroll
    for (int c = 0; c < 4; ++c) bvv[c] = bias[c0 + c];
#pragma unroll
    for (int r = 0; r < 4; ++r) {
        int row = row0 + ty * 4 + r;
        if (row < n) {
            float4 o;
            o.x = acc[r][0] + bvv[0]; o.y = acc[r][1] + bvv[1];
            o.z = acc[r][2] + bvv[2]; o.w = acc[r][3] + bvv[3];
            *(float4*)&H[(size_t)row * 128 + c0] = o;
        }
    }
}

__global__ void scale_init(const float* __restrict__ h, float* __restrict__ z,
                           const float* __restrict__ eps, int layer, int n4)
{
    const float s = 1.0f + eps[layer];
    int i = blockIdx.x * blockDim.x + threadIdx.x;
    const int stride = gridDim.x * blockDim.x;
    const float4* h4 = (const float4*)h;
    float4* z4 = (float4*)z;
    for (; i < n4; i += stride) {
        float4 v = h4[i];
        v.x *= s; v.y *= s; v.z *= s; v.w *= s;
        z4[i] = v;
    }
}

__global__ __launch_bounds__(256) void edge_atomic(
    const float* __restrict__ h, const int* __restrict__ ei,
    const float* __restrict__ eattr, const float* __restrict__ eatten,
    const float* __restrict__ W_ee, const float* __restrict__ b_ee,
    float* __restrict__ Z, int E)
{
    __shared__ float Wee[16][128];
    __shared__ float bee[128];
    const int t = threadIdx.x;
    const float4* We4 = (const float4*)W_ee;
    float4* Ws4 = (float4*)&Wee[0][0];
#pragma unroll
    for (int i = 0; i < 2; ++i) Ws4[t + 256 * i] = We4[t + 256 * i];
    if (t < 128) bee[t] = b_ee[t];
    __syncthreads();

    const int lane = t & 63;
    const int c = lane * 2;
    const long wid = (long)blockIdx.x * 4 + (t >> 6);
    const long nw = (long)gridDim.x * 4;
    for (long e = wid; e < E; e += nw) {
        const int src = ei[e];
        const int dst = ei[E + e];
        const float att = eatten[e];
        union { float4 v4[4]; float f[16]; } ea;
        const float4* eap = (const float4*)(eattr + e * 16);
        ea.v4[0] = eap[0]; ea.v4[1] = eap[1]; ea.v4[2] = eap[2]; ea.v4[3] = eap[3];
        float2 hv = *(const float2*)&h[(size_t)src * 128 + c];
        float e0 = bee[c], e1 = bee[c + 1];
#pragma unroll
        for (int k = 0; k < 16; ++k) {
            float2 w = *(const float2*)&Wee[k][c];
            e0 = fmaf(ea.f[k], w.x, e0);
            e1 = fmaf(ea.f[k], w.y, e1);
        }
        float m0 = fmaxf(hv.x + e0, 0.f) * att;
        float m1 = fmaxf(hv.y + e1, 0.f) * att;
        atomic_add2(&Z[(size_t)dst * 128 + c], m0, m1);
    }
}

__global__ __launch_bounds__(512, 4) void gemm_mlp(
    const float* __restrict__ Z,
    const float* __restrict__ W1, const float* __restrict__ b1,
    const float* __restrict__ gam, const float* __restrict__ bet,
    const float* __restrict__ mu, const float* __restrict__ var,
    const float* __restrict__ W2, const float* __restrict__ b2,
    float* __restrict__ H, int n)
{
    __shared__ float At[64][128];
    __shared__ float Wb[2][16][128];
    const int t = threadIdx.x;
    const int tx = t & 31, ty = t >> 5;

    const int row0 = blockIdx.x * 64;
    const int nrows = min(64, n - row0);
    const int lim = nrows * 32;
    const float4* Z4 = (const float4*)(Z + (size_t)row0 * 128);
    float4* At4 = (float4*)&At[0][0];
#pragma unroll
    for (int i = 0; i < 4; ++i) {
        int idx = t + 512 * i;
        if (idx < lim) At4[idx] = Z4[idx];
    }
    const float4* W14 = (const float4*)W1;
    ((float4*)&Wb[0][0][0])[t] = W14[t];
    __syncthreads();

    float acc[4][4] = {};
    for (int c = 0; c < 8; ++c) {
        const int buf = c & 1;
        float4 wnext;
        if (c < 7) wnext = W14[(c + 1) * 512 + t];
#pragma unroll
        for (int g = 0; g < 4; ++g) {
            float4 w4[4];
#pragma unroll
            for (int kk = 0; kk < 4; ++kk) w4[kk] = *(const float4*)&Wb[buf][g * 4 + kk][tx * 4];
#pragma unroll
            for (int r = 0; r < 4; ++r) {
                float4 a = *(const float4*)&At[ty * 4 + r][c * 16 + g * 4];
                float ar[4] = {a.x, a.y, a.z, a.w};
#pragma unroll
                for (int kk = 0; kk < 4; ++kk) {
                    acc[r][0] = fmaf(ar[kk], w4[kk].x, acc[r][0]);
                    acc[r][1] = fmaf(ar[kk], w4[kk].y, acc[r][1]);
                    acc[r][2] = fmaf(ar[kk], w4[kk].z, acc[r][2]);
                    acc[r][3] = fmaf(ar[kk], w4[kk].w, acc[r][3]);
                }
            }
        }
        if (c < 7) ((float4*)&Wb[buf ^ 1][0][0])[t] = wnext;
        __syncthreads();
    }

    const int c0 = tx * 4;
    const float4* W24 = (const float4*)W2;
    float4 w2pre = W24[t];
    {
        float b1v[4], scv[4], shv[4];
#pragma unroll
        for (int cl = 0; cl < 4; ++cl) {
            b1v[cl] = b1[c0 + cl];
            float s = gam[c0 + cl] * rsqrtf(var[c0 + cl] + 1e-5f);
            scv[cl] = s;
            shv[cl] = bet[c0 + cl] - mu[c0 + cl] * s;
        }
#pragma unroll
        for (int r = 0; r < 4; ++r) {
            float4 y;
            y.x = fmaxf(fmaf(acc[r][0] + b1v[0], scv[0], shv[0]), 0.f);
            y.y = fmaxf(fmaf(acc[r][1] + b1v[1], scv[1], shv[1]), 0.f);
            y.z = fmaxf(fmaf(acc[r][2] + b1v[2], scv[2], shv[2]), 0.f);
            y.w = fmaxf(fmaf(acc[r][3] + b1v[3], scv[3], shv[3]), 0.f);
            *(float4*)&At[ty * 4 + r][c0] = y;
            acc[r][0] = 0.f; acc[r][1] = 0.f; acc[r][2] = 0.f; acc[r][3] = 0.f;
        }
    }
    ((float4*)&Wb[0][0][0])[t] = w2pre;
    __syncthreads();

    for (int c = 0; c < 8; ++c) {
        const int buf = c & 1;
        float4 wnext;
        if (c < 7) wnext = W24[(c + 1) * 512 + t];
#pragma unroll
        for (int g = 0; g < 4; ++g) {
            float4 w4[4];
#pragma unroll
            for (int kk = 0; kk < 4; ++kk) w4[kk] = *(const float4*)&Wb[buf][g * 4 + kk][tx * 4];
#pragma unroll
            for (int r = 0; r < 4; ++r) {
                float4 a = *(const float4*)&At[ty * 4 + r][c * 16 + g * 4];
                float ar[4] = {a.x, a.y, a.z, a.w};
#pragma unroll
                for (int kk = 0; kk < 4; ++kk) {
                    acc[r][0] = fmaf(ar[kk], w4[kk].x, acc[r][0]);
                    acc[r][1] = fmaf(ar[kk], w4[kk].y, acc[r][1]);
                    acc[r][2] = fmaf(ar[kk], w4[kk].z, acc[r][2]);
                    acc[r][3] = fmaf(ar[kk], w4[kk].w, acc[r][3]);
                }
            }
        }
        if (c < 7) ((float4*)&Wb[buf ^ 1][0][0])[t] = wnext;
        __syncthreads();
    }

    float b2v[4];
#pragma unroll
    for (int cl = 0; cl < 4; ++cl) b2v[cl] = b2[c0 + cl];
#pragma unroll
    for (int r = 0; r < 4; ++r) {
        int row = row0 + ty * 4 + r;
        if (row < n) {
            float4 o;
            o.x = fmaxf(acc[r][0] + b2v[0], 0.f);
            o.y = fmaxf(acc[r][1] + b2v[1], 0.f);
            o.z = fmaxf(acc[r][2] + b2v[2], 0.f);
            o.w = fmaxf(acc[r][3] + b2v[3], 0.f);
            *(float4*)&H[(size_t)row * 128 + c0] = o;
        }
    }
}

extern "C" void kernel_launch(void* const* d_in, const int* in_sizes, int n_in,
                              void* d_out, int out_size, void* d_ws, size_t ws_size,
                              hipStream_t stream)
{
    const float* x      = (const float*)d_in[0];
    const int*   ei     = (const int*)d_in[1];
    // d_in[2] = batch (unused)
    const float* eattr  = (const float*)d_in[3];
    const float* eatten = (const float*)d_in[4];
    const float* W_enc  = (const float*)d_in[5];
    const float* b_enc  = (const float*)d_in[6];
    const float* W_ee   = (const float*)d_in[7];
    const float* b_ee   = (const float*)d_in[8];
    const float* eps    = (const float*)d_in[9];
    const float* W1     = (const float*)d_in[10];
    const float* b1     = (const float*)d_in[11];
    const float* gam    = (const float*)d_in[12];
    const float* bet    = (const float*)d_in[13];
    const float* mu     = (const float*)d_in[14];
    const float* var    = (const float*)d_in[15];
    const float* W2     = (const float*)d_in[16];
    const float* b2     = (const float*)d_in[17];

    const int N = in_sizes[0] / 128;
    const int E = in_sizes[1] / 2;
    const int L = in_sizes[9];
    const int Scap = E + N;      // max padded slots

    float* hout = (float*)d_out;   // final f32 output

    // workspace layout (main path). x16 aliases z16 (x16 dead after enc).
    char* p = (char*)d_ws;
    _Float16* z16 = (_Float16*)p;       p += ((size_t)N * 128 * 2 + 255) & ~(size_t)255;
    _Float16* h16 = (_Float16*)p;       p += ((size_t)N * 128 * 2 + 255) & ~(size_t)255;
    int* off  = (int*)p;                p += 4 * (size_t)(N + 1);
    int* cur  = (int*)p;                p += 4 * (size_t)N;
    int* cnt  = (int*)p;                p += 4 * (size_t)N;
    int* bsum = (int*)p;                p += 4 * 1024;
    int* eids = (int*)p;                p += 4 * (size_t)Scap;
    p = (char*)(((uintptr_t)p + 255) & ~(uintptr_t)255);
    float2* sat = (float2*)p;           p += 8 * (size_t)Scap;
    p = (char*)(((uintptr_t)p + 255) & ~(uintptr_t)255);
    uint16_t* eab8 = (uint16_t*)p;      p += 256 * (size_t)((Scap + 1) / 2);
    p = (char*)(((uintptr_t)p + 255) & ~(uintptr_t)255);
    _Float16* Wpk = (_Float16*)p;       p += (2 * (size_t)L + 1) * 32 * 512 * 2;
    const size_t need_main = (size_t)(p - (char*)d_ws);

    const bool use_main = ws_size >= need_main;
    const int tiles = (N + 63) / 64;
    const int NB = (N + 1023) / 1024;

    if (use_main) {
        _Float16* x16 = z16;   // alias: x16 dead once layer-0 agg writes z16

        init_arrays<<<1024, 256, 0, stream>>>(cnt, N, eids, Scap);
        hist_kernel<<<1024, 256, 0, stream>>>(ei, cnt, E);
        scan_pass1<<<NB, 256, 0, stream>>>(cnt, bsum, N);
        scan_pass2<<<1, 256, 0, stream>>>(bsum, off, NB, N);
        scan_pass3<<<NB, 256, 0, stream>>>(cnt, bsum, off, cur, N);
        scatter_kernel<<<1024, 256, 0, stream>>>(ei, cur, eids, E);
        permute_sat<<<1024, 256, 0, stream>>>(ei, eatten, eids, off + N, sat, Scap);
        eabuild_staged<<<(Scap + 255) / 256, 256, 0, stream>>>(
            eids, eattr, W_ee, b_ee, off + N, eab8, Scap);
        prepack_w<<<((2 * L + 1) * 32 * 64 + 255) / 256, 256, 0, stream>>>(
            W1, W2, W_enc, Wpk, L);

        cvt_f16<<<2048, 256, 0, stream>>>(x, x16, N * 128 / 8);
        enc_mfma<<<tiles, 256, 0, stream>>>(
            x16, Wpk + (size_t)(2 * L) * 32 * 512, b_enc, h16, N);

        for (int i = 0; i < L; ++i) {
            agg_f8<<<(N + 3) / 4, 256, 0, stream>>>(
                h16, sat, (const uint32_t*)eab8, off, z16, eps, i, N);
            mlp_mfma<<<tiles, 256, 0, stream>>>(
                z16,
                Wpk + (size_t)i * 32 * 512, b1 + i * 128,
                gam + i * 128, bet + i * 128, mu + i * 128, var + i * 128,
                Wpk + (size_t)(L + i) * 32 * 512, b2 + i * 128,
                h16, hout, (i == L - 1) ? 1 : 0, N);
        }
        return;
    }

    // fallback: f32 atomic tier (zbuf at ws start)
    float* zbuf = (float*)d_ws;
    float* h = hout;
    gemm_enc<<<tiles, 512, 0, stream>>>(x, W_enc, b_enc, h, N);
    for (int i = 0; i < L; ++i) {
        scale_init<<<2048, 256, 0, stream>>>(h, zbuf, eps, i, N * 128 / 4);
        edge_atomic<<<2048, 256, 0, stream>>>(h, ei, eattr, eatten, W_ee, b_ee, zbuf, E);
        gemm_mlp<<<tiles, 512, 0, stream>>>(
            zbuf, W1 + (size_t)i * 128 * 128, b1 + i * 128,
            gam + i * 128, bet + i * 128, mu + i * 128, var + i * 128,
            W2 + (size_t)i * 128 * 128, b2 + i * 128,
            h, N);
    }
}

// Round 16
// 408.946 us; speedup vs baseline: 1.6195x; 1.0352x over previous
//
#include <hip/hip_runtime.h>
#include <hip/hip_fp16.h>
#include <cstdint>
#include <cstddef>

// ---------------------------------------------------------------------------
// GIN (GINEConv x3) forward. f32 in/out; f16 h/z; FP8(e4m3) precomputed ea.
//   x16 = f16(x); h16 = x16@W_enc + b (enc_mfma)
//   CSR (deg padded even) -> eabuild_mfma: sat{src,att} + eab8 (fp8 ea,
//     pair-interleaved; ea computed on the MFMA pipe)
//   per layer: agg_f8 (h16 gather + fp8 ea decode) -> z16
//              mlp_mfma (16x16x32 f16) -> h16 (last layer: f32 d_out)
// ---------------------------------------------------------------------------

typedef _Float16 f16x8 __attribute__((ext_vector_type(8)));
typedef float    f32x4 __attribute__((ext_vector_type(4)));
typedef float    f32x2 __attribute__((ext_vector_type(2)));

// ---- fp8 e4m3 pack/unpack with compile-safe fallback ----------------------
__device__ inline uint32_t pack_fp8_pair(float a, float b) {
#if __has_builtin(__builtin_amdgcn_cvt_pk_fp8_f32)
    return (uint32_t)__builtin_amdgcn_cvt_pk_fp8_f32(a, b, 0, false) & 0xFFFFu;
#else
    auto enc = [](float x) -> uint32_t {
        uint32_t s = (x < 0.f) ? 0x80u : 0u;
        float ax = fabsf(x);
        if (!(ax >= 1.953125e-3f)) {             // subnormal / zero
            int mi = (int)(ax * 512.f + 0.5f);
            if (mi > 7) mi = 7;
            return s | (uint32_t)mi;
        }
        ax = fminf(ax, 448.f);
        int e; float m = frexpf(ax, &e);         // ax = m * 2^e, m in [0.5,1)
        int E = e - 1 + 7;
        int mi = (int)((m * 2.f - 1.f) * 8.f + 0.5f);
        if (mi == 8) { mi = 0; ++E; }
        if (E > 15 || (E == 15 && mi == 7)) { E = 15; mi = 6; }
        return s | ((uint32_t)E << 3) | (uint32_t)mi;
    };
    return enc(a) | (enc(b) << 8);
#endif
}

template <bool HIGH>
__device__ inline f32x2 unpack_fp8_pair(uint32_t w) {
#if __has_builtin(__builtin_amdgcn_cvt_pk_f32_fp8)
    return __builtin_amdgcn_cvt_pk_f32_fp8((int)w, HIGH);
#else
    auto dec = [](uint32_t v) -> float {
        uint32_t s = v >> 7, e = (v >> 3) & 0xF, m = v & 7;
        float r = (e == 0) ? ldexpf((float)m, -9)
                           : ldexpf(1.f + (float)m / 8.f, (int)e - 7);
        return s ? -r : r;
    };
    uint32_t b0 = HIGH ? ((w >> 16) & 0xFF) : (w & 0xFF);
    uint32_t b1 = HIGH ? ((w >> 24) & 0xFF) : ((w >> 8) & 0xFF);
    return (f32x2){dec(b0), dec(b1)};
#endif
}

// ---- packed-f32x2 atomic with compile-safe fallback (fallback tier only) ---
template <class T>
__device__ inline auto add2_impl(T* p, T v, int)
    -> decltype(unsafeAtomicAdd(p, v), void()) {
    unsafeAtomicAdd(p, v);
}
template <class T>
__device__ inline void add2_impl(T* p, T v, long) {
    unsafeAtomicAdd(&p->x, v.x);
    unsafeAtomicAdd(&p->y, v.y);
}
__device__ inline void atomic_add2(float* p, float x, float y) {
    add2_impl(reinterpret_cast<float2*>(p), make_float2(x, y), 0);
}

// ---------------------------------------------------------------------------
// CSR build
// ---------------------------------------------------------------------------
__global__ void init_arrays(int* __restrict__ cnt, int N, int* __restrict__ eids, int S)
{
    int i = blockIdx.x * blockDim.x + threadIdx.x;
    const int st = gridDim.x * blockDim.x;
    for (int j = i; j < N; j += st) cnt[j] = 0;
    for (int j = i; j < S; j += st) eids[j] = -1;
}

__global__ void hist_kernel(const int* __restrict__ ei, int* __restrict__ cnt, int E)
{
    int i = blockIdx.x * blockDim.x + threadIdx.x;
    const int st = gridDim.x * blockDim.x;
    for (; i < E; i += st) atomicAdd(&cnt[ei[E + i]], 1);
}

__global__ __launch_bounds__(256) void scan_pass1(
    const int* __restrict__ cnt, int* __restrict__ bsum, int N)
{
    __shared__ int part[256];
    const int t = threadIdx.x;
    const int base = blockIdx.x * 1024 + t * 4;
    int s = 0;
#pragma unroll
    for (int j = 0; j < 4; ++j) {
        int idx = base + j;
        if (idx < N) { int v = cnt[idx]; s += v + (v & 1); }
    }
    part[t] = s;
    __syncthreads();
    for (int d = 128; d > 0; d >>= 1) {
        if (t < d) part[t] += part[t + d];
        __syncthreads();
    }
    if (t == 0) bsum[blockIdx.x] = part[0];
}

__global__ __launch_bounds__(256) void scan_pass2(
    int* __restrict__ bsum, int* __restrict__ off, int NB, int N)
{
    __shared__ int sb[1024];
    const int t = threadIdx.x;
    for (int i = t; i < NB; i += 256) sb[i] = bsum[i];
    __syncthreads();
    if (t == 0) {
        int run = 0;
        for (int i = 0; i < NB; ++i) { int v = sb[i]; sb[i] = run; run += v; }
        off[N] = run;          // total padded slots S
    }
    __syncthreads();
    for (int i = t; i < NB; i += 256) bsum[i] = sb[i];
}

__global__ __launch_bounds__(256) void scan_pass3(
    const int* __restrict__ cnt, const int* __restrict__ bsum,
    int* __restrict__ off, int* __restrict__ cur, int N)
{
    __shared__ int part[256];
    const int t = threadIdx.x;
    const int base = blockIdx.x * 1024 + t * 4;
    int pv[4]; int s = 0;
#pragma unroll
    for (int j = 0; j < 4; ++j) {
        int idx = base + j;
        int v = (idx < N) ? cnt[idx] : 0;
        pv[j] = v + (v & 1);
        s += pv[j];
    }
    part[t] = s;
    __syncthreads();
    for (int d = 1; d < 256; d <<= 1) {
        int x = (t >= d) ? part[t - d] : 0;
        __syncthreads();
        part[t] += x;
        __syncthreads();
    }
    int run = bsum[blockIdx.x] + part[t] - s;
#pragma unroll
    for (int j = 0; j < 4; ++j) {
        int idx = base + j;
        if (idx < N) { off[idx] = run; cur[idx] = run; }
        run += pv[j];
    }
}

__global__ void scatter_kernel(const int* __restrict__ ei, int* __restrict__ cur,
                               int* __restrict__ eids, int E)
{
    int i = blockIdx.x * blockDim.x + threadIdx.x;
    const int st = gridDim.x * blockDim.x;
    for (; i < E; i += st) {
        int pos = atomicAdd(&cur[ei[E + i]], 1);
        eids[pos] = i;
    }
}

// ---------------------------------------------------------------------------
// eabuild_mfma: per 256-slot block:
//   stage eids; write sat{src,att}; stage attr rows as f16 in LDS;
//   per wave: 4 tiles of 16 slots, ea = attr@W_ee via 8 MFMAs -> LDS;
//   pack (ea + b_ee) to fp8, pair-interleaved u32 writes.
// Layout (agg-compatible): u32 at [pair*64 + lane] = {even slot c,c+1 | odd<<16}.
// ---------------------------------------------------------------------------
__global__ __launch_bounds__(256) void eabuild_mfma(
    const int* __restrict__ eids, const float* __restrict__ eattr,
    const int* __restrict__ ei, const float* __restrict__ eatten,
    const float* __restrict__ W_ee, const float* __restrict__ b_ee,
    const int* __restrict__ offN, uint32_t* __restrict__ eab32,
    float2* __restrict__ sat, int Scap)
{
    __shared__ int      se[256];            // 1 KB
    __shared__ _Float16 sattr16[256][16];   // 8 KB
    __shared__ float    eaL[4][16][132];    // 33 KB (per-wave tiles)
    const int t = threadIdx.x;
    const int lane = t & 63;
    const int w = t >> 6;
    const int lr = lane & 15;
    const int lg = lane >> 4;
    const int c = lane * 2;

    const int S = *offN;
    const int base = blockIdx.x * 256;
    const int n = min(256, S - base);
    if (n <= 0) return;

    // B fragments of W_ee: col = tc*16+lr, k = lg*8+i (k<16 real, else 0)
    f16x8 bfrag[8];
#pragma unroll
    for (int tc = 0; tc < 8; ++tc) {
        f16x8 b = {};
        if (lg < 2) {
#pragma unroll
            for (int i = 0; i < 8; ++i)
                b[i] = (_Float16)W_ee[(lg * 8 + i) * 128 + tc * 16 + lr];
        }
        bfrag[tc] = b;
    }
    const float2 bv = *(const float2*)&b_ee[c];

    if (t < n) se[t] = eids[base + t];
    __syncthreads();

    // sat write + attr -> f16 LDS (zero rows >= n)
    if (t < n) {
        const int eid = se[t];
        float2 v;
        f16x8 lo = {}, hi = {};
        if (eid >= 0) {
            v.x = __int_as_float(ei[eid]); v.y = eatten[eid];
            const float4* ep = (const float4*)(eattr + (size_t)eid * 16);
            float4 e0 = ep[0], e1 = ep[1], e2 = ep[2], e3 = ep[3];
            lo = (f16x8){(_Float16)e0.x, (_Float16)e0.y, (_Float16)e0.z, (_Float16)e0.w,
                         (_Float16)e1.x, (_Float16)e1.y, (_Float16)e1.z, (_Float16)e1.w};
            hi = (f16x8){(_Float16)e2.x, (_Float16)e2.y, (_Float16)e2.z, (_Float16)e2.w,
                         (_Float16)e3.x, (_Float16)e3.y, (_Float16)e3.z, (_Float16)e3.w};
        } else {
            v.x = __int_as_float(0); v.y = 0.f;
        }
        sat[base + t] = v;
        *(f16x8*)&sattr16[t][0] = lo;
        *(f16x8*)&sattr16[t][8] = hi;
    } else {
        *(f16x8*)&sattr16[t][0] = (f16x8){};
        *(f16x8*)&sattr16[t][8] = (f16x8){};
    }
    __syncthreads();

    // per wave: 4 tiles of 16 slots
#pragma unroll
    for (int k = 0; k < 4; ++k) {
        const int tb = w * 64 + k * 16;          // tile base (block-local)
        if (tb >= n) break;
        f16x8 af = {};
        if (lg < 2)
            af = *(const f16x8*)&sattr16[tb + lr][lg * 8];
#pragma unroll
        for (int tc = 0; tc < 8; ++tc) {
            f32x4 acc = __builtin_amdgcn_mfma_f32_16x16x32_f16(
                af, bfrag[tc], (f32x4){0.f, 0.f, 0.f, 0.f}, 0, 0, 0);
#pragma unroll
            for (int j = 0; j < 4; ++j)
                eaL[w][lg * 4 + j][tc * 16 + lr] = acc[j];
        }
        // pack lane's 2 cols for 8 slot-pairs (n even -> no pair straddle)
#pragma unroll
        for (int pp = 0; pp < 8; ++pp) {
            const int s0 = tb + 2 * pp;
            if (s0 >= n) break;
            float2 ea0 = *(const float2*)&eaL[w][2 * pp][c];
            float2 ea1 = *(const float2*)&eaL[w][2 * pp + 1][c];
            uint32_t p0 = pack_fp8_pair(ea0.x + bv.x, ea0.y + bv.y);
            uint32_t p1 = pack_fp8_pair(ea1.x + bv.x, ea1.y + bv.y);
            eab32[(size_t)((base + s0) >> 1) * 64 + lane] = p0 | (p1 << 16);
        }
    }
}

// ---------------------------------------------------------------------------
// prepack W1/W2/W_enc into MFMA B-fragment order (f16).
// ---------------------------------------------------------------------------
__global__ void prepack_w(const float* __restrict__ W1, const float* __restrict__ W2,
                          const float* __restrict__ Wenc,
                          _Float16* __restrict__ Wpk, int L)
{
    int tid = blockIdx.x * blockDim.x + threadIdx.x;
    const int total = (2 * L + 1) * 32 * 64;
    if (tid >= total) return;
    const int lane = tid & 63;
    const int f = (tid >> 6) & 31;
    const int lm = tid >> 11;
    const int kb = f >> 3, tc = f & 7;
    const float* src = (lm < L) ? (W1 + (size_t)lm * 16384)
                    : (lm < 2 * L) ? (W2 + (size_t)(lm - L) * 16384)
                    : Wenc;
    _Float16* dst = Wpk + ((size_t)lm * 32 + f) * 512 + lane * 8;
#pragma unroll
    for (int i = 0; i < 8; ++i) {
        const int k = kb * 32 + (lane >> 4) * 8 + i;
        const int col = tc * 16 + (lane & 15);
        dst[i] = (_Float16)src[k * 128 + col];
    }
}

// f32 -> f16 bulk convert (8 elems/thread)
__global__ void cvt_f16(const float* __restrict__ x, _Float16* __restrict__ y, int n8)
{
    int i = blockIdx.x * blockDim.x + threadIdx.x;
    const int st = gridDim.x * blockDim.x;
    for (; i < n8; i += st) {
        float4 a = ((const float4*)x)[2 * i];
        float4 b = ((const float4*)x)[2 * i + 1];
        f16x8 v = {(_Float16)a.x, (_Float16)a.y, (_Float16)a.z, (_Float16)a.w,
                   (_Float16)b.x, (_Float16)b.y, (_Float16)b.z, (_Float16)b.w};
        ((f16x8*)y)[i] = v;
    }
}

// ---------------------------------------------------------------------------
// Encoder MFMA: h16 = x16 @ W_enc + b_enc.
// ---------------------------------------------------------------------------
__global__ __launch_bounds__(256) void enc_mfma(
    const _Float16* __restrict__ x16, const _Float16* __restrict__ Wpk,
    const float* __restrict__ bias, _Float16* __restrict__ h16, int n)
{
    const int t = threadIdx.x;
    const int lane = t & 63;
    const int w = t >> 6;
    const int row0 = blockIdx.x * 64;
    const int lr = lane & 15;
    const int lg = lane >> 4;

    f32x4 acc[8];
#pragma unroll
    for (int tc = 0; tc < 8; ++tc) acc[tc] = (f32x4){0.f, 0.f, 0.f, 0.f};
    const int arow = min(row0 + w * 16 + lr, n - 1);
#pragma unroll
    for (int kb = 0; kb < 4; ++kb) {
        f16x8 a = *(const f16x8*)&x16[(size_t)arow * 128 + kb * 32 + lg * 8];
#pragma unroll
        for (int tc = 0; tc < 8; ++tc) {
            f16x8 b = *(const f16x8*)&Wpk[((kb * 8 + tc) * 64 + lane) * 8];
            acc[tc] = __builtin_amdgcn_mfma_f32_16x16x32_f16(a, b, acc[tc], 0, 0, 0);
        }
    }
#pragma unroll
    for (int tc = 0; tc < 8; ++tc) {
        const int col = tc * 16 + lr;
        const float bb = bias[col];
#pragma unroll
        for (int j = 0; j < 4; ++j) {
            const int row = row0 + w * 16 + lg * 4 + j;
            if (row < n)
                h16[(size_t)row * 128 + col] = (_Float16)(acc[tc][j] + bb);
        }
    }
}

// ---------------------------------------------------------------------------
// Aggregation: one wave per node, lane owns 2 cols. h16 gather + fp8 ea.
// ---------------------------------------------------------------------------
__global__ __launch_bounds__(256) void agg_f8(
    const _Float16* __restrict__ h16, const float2* __restrict__ sat,
    const uint32_t* __restrict__ eab8, const int* __restrict__ off,
    _Float16* __restrict__ z16, const float* __restrict__ eps, int layer, int N)
{
    const int t = threadIdx.x;
    const int v = blockIdx.x * 4 + (t >> 6);
    if (v >= N) return;
    const int lane = t & 63;
    const int c = lane * 2;

    const int e0 = off[v], e1 = off[v + 1];   // even-aligned, even length
    float a0 = 0.f, a1 = 0.f;
    int e = e0;
    for (; e + 8 <= e1; e += 8) {
        float4 sa[2];
        sa[0] = *(const float4*)&sat[e];
        sa[1] = *(const float4*)&sat[e + 2];
        float4 sb[2];
        sb[0] = *(const float4*)&sat[e + 4];
        sb[1] = *(const float4*)&sat[e + 6];
        uint32_t eb[4];
#pragma unroll
        for (int j = 0; j < 4; ++j)
            eb[j] = eab8[(size_t)((e >> 1) + j) * 64 + lane];
        uint32_t hv[8];
        hv[0] = *(const uint32_t*)&h16[(size_t)__float_as_int(sa[0].x) * 128 + c];
        hv[1] = *(const uint32_t*)&h16[(size_t)__float_as_int(sa[0].z) * 128 + c];
        hv[2] = *(const uint32_t*)&h16[(size_t)__float_as_int(sa[1].x) * 128 + c];
        hv[3] = *(const uint32_t*)&h16[(size_t)__float_as_int(sa[1].z) * 128 + c];
        hv[4] = *(const uint32_t*)&h16[(size_t)__float_as_int(sb[0].x) * 128 + c];
        hv[5] = *(const uint32_t*)&h16[(size_t)__float_as_int(sb[0].z) * 128 + c];
        hv[6] = *(const uint32_t*)&h16[(size_t)__float_as_int(sb[1].x) * 128 + c];
        hv[7] = *(const uint32_t*)&h16[(size_t)__float_as_int(sb[1].z) * 128 + c];
#pragma unroll
        for (int j = 0; j < 4; ++j) {
            const float4 s4 = (j < 2) ? sa[j] : sb[j - 2];
            f32x2 ev = unpack_fp8_pair<false>(eb[j]);
            f32x2 od = unpack_fp8_pair<true>(eb[j]);
            __half2 h0 = *reinterpret_cast<const __half2*>(&hv[2 * j]);
            __half2 h1 = *reinterpret_cast<const __half2*>(&hv[2 * j + 1]);
            a0 += fmaxf(__half2float(__low2half(h0))  + ev[0], 0.f) * s4.y;
            a1 += fmaxf(__half2float(__high2half(h0)) + ev[1], 0.f) * s4.y;
            a0 += fmaxf(__half2float(__low2half(h1))  + od[0], 0.f) * s4.w;
            a1 += fmaxf(__half2float(__high2half(h1)) + od[1], 0.f) * s4.w;
        }
    }
    for (; e < e1; e += 2) {
        float4 sa = *(const float4*)&sat[e];
        uint32_t eb = eab8[(size_t)(e >> 1) * 64 + lane];
        uint32_t hv0 = *(const uint32_t*)&h16[(size_t)__float_as_int(sa.x) * 128 + c];
        uint32_t hv1 = *(const uint32_t*)&h16[(size_t)__float_as_int(sa.z) * 128 + c];
        f32x2 ev = unpack_fp8_pair<false>(eb);
        f32x2 od = unpack_fp8_pair<true>(eb);
        __half2 h0 = *reinterpret_cast<const __half2*>(&hv0);
        __half2 h1 = *reinterpret_cast<const __half2*>(&hv1);
        a0 += fmaxf(__half2float(__low2half(h0))  + ev[0], 0.f) * sa.y;
        a1 += fmaxf(__half2float(__high2half(h0)) + ev[1], 0.f) * sa.y;
        a0 += fmaxf(__half2float(__low2half(h1))  + od[0], 0.f) * sa.w;
        a1 += fmaxf(__half2float(__high2half(h1)) + od[1], 0.f) * sa.w;
    }

    const float sc = 1.0f + eps[layer];
    uint32_t hvv = *(const uint32_t*)&h16[(size_t)v * 128 + c];
    __half2 hh = *reinterpret_cast<const __half2*>(&hvv);
    float zx = fmaf(sc, __half2float(__low2half(hh)), a0);
    float zy = fmaf(sc, __half2float(__high2half(hh)), a1);
    __half2 zz = __floats2half2_rn(zx, zy);
    *reinterpret_cast<__half2*>(&z16[(size_t)v * 128 + c]) = zz;
}

// ---------------------------------------------------------------------------
// MFMA MLP: out = relu( relu(BN(z16@W1+b1)) @ W2 + b2 ).
// last==0: write h16 (f16); last==1: write f32 H.
// ---------------------------------------------------------------------------
__global__ __launch_bounds__(256) void mlp_mfma(
    const _Float16* __restrict__ z16,
    const _Float16* __restrict__ W1pk, const float* __restrict__ b1,
    const float* __restrict__ gam, const float* __restrict__ bet,
    const float* __restrict__ mu, const float* __restrict__ var,
    const _Float16* __restrict__ W2pk, const float* __restrict__ b2,
    _Float16* __restrict__ h16out, float* __restrict__ H, int last, int n)
{
    __shared__ _Float16 Yt[64][136];   // padded: 2-way banks
    const int t = threadIdx.x;
    const int lane = t & 63;
    const int w = t >> 6;
    const int row0 = blockIdx.x * 64;
    const int lr = lane & 15;
    const int lg = lane >> 4;

    f32x4 acc[8];
#pragma unroll
    for (int tc = 0; tc < 8; ++tc) acc[tc] = (f32x4){0.f, 0.f, 0.f, 0.f};
    const int arow = min(row0 + w * 16 + lr, n - 1);
#pragma unroll
    for (int kb = 0; kb < 4; ++kb) {
        f16x8 a = *(const f16x8*)&z16[(size_t)arow * 128 + kb * 32 + lg * 8];
#pragma unroll
        for (int tc = 0; tc < 8; ++tc) {
            f16x8 b = *(const f16x8*)&W1pk[((kb * 8 + tc) * 64 + lane) * 8];
            acc[tc] = __builtin_amdgcn_mfma_f32_16x16x32_f16(a, b, acc[tc], 0, 0, 0);
        }
    }
#pragma unroll
    for (int tc = 0; tc < 8; ++tc) {
        const int col = tc * 16 + lr;
        const float s  = gam[col] * rsqrtf(var[col] + 1e-5f);
        const float sh = bet[col] - mu[col] * s;
        const float bb = b1[col];
#pragma unroll
        for (int j = 0; j < 4; ++j) {
            float y = fmaxf(fmaf(acc[tc][j] + bb, s, sh), 0.f);
            Yt[w * 16 + lg * 4 + j][col] = (_Float16)y;
        }
    }
    __syncthreads();

#pragma unroll
    for (int tc = 0; tc < 8; ++tc) acc[tc] = (f32x4){0.f, 0.f, 0.f, 0.f};
#pragma unroll
    for (int kb = 0; kb < 4; ++kb) {
        f16x8 a = *(const f16x8*)&Yt[w * 16 + lr][kb * 32 + lg * 8];
#pragma unroll
        for (int tc = 0; tc < 8; ++tc) {
            f16x8 b = *(const f16x8*)&W2pk[((kb * 8 + tc) * 64 + lane) * 8];
            acc[tc] = __builtin_amdgcn_mfma_f32_16x16x32_f16(a, b, acc[tc], 0, 0, 0);
        }
    }
#pragma unroll
    for (int tc = 0; tc < 8; ++tc) {
        const int col = tc * 16 + lr;
        const float bb = b2[col];
#pragma unroll
        for (int j = 0; j < 4; ++j) {
            const int row = row0 + w * 16 + lg * 4 + j;
            if (row < n) {
                const float o = fmaxf(acc[tc][j] + bb, 0.f);
                if (last) H[(size_t)row * 128 + col] = o;
                else      h16out[(size_t)row * 128 + col] = (_Float16)o;
            }
        }
    }
}

// ---------------------------------------------------------------------------
// Fallback tier (f32 end-to-end): gemm_enc + scale_init + atomic + gemm_mlp
// ---------------------------------------------------------------------------
__global__ __launch_bounds__(512, 4) void gemm_enc(
    const float* __restrict__ A, const float* __restrict__ W,
    const float* __restrict__ bias, float* __restrict__ H, int n)
{
    __shared__ float At[64][128];
    __shared__ float Wb[2][16][128];
    const int t = threadIdx.x;
    const int tx = t & 31, ty = t >> 5;

    const int row0 = blockIdx.x * 64;
    const int nrows = min(64, n - row0);
    const int lim = nrows * 32;
    const float4* A4 = (const float4*)(A + (size_t)row0 * 128);
    float4* At4 = (float4*)&At[0][0];
#pragma unroll
    for (int i = 0; i < 4; ++i) {
        int idx = t + 512 * i;
        if (idx < lim) At4[idx] = A4[idx];
    }
    const float4* W4 = (const float4*)W;
    ((float4*)&Wb[0][0][0])[t] = W4[t];
    __syncthreads();

    float acc[4][4] = {};
    for (int c = 0; c < 8; ++c) {
        const int buf = c & 1;
        float4 wnext;
        if (c < 7) wnext = W4[(c + 1) * 512 + t];
#pragma unroll
        for (int g = 0; g < 4; ++g) {
            float4 w4[4];
#pragma unroll
            for (int kk = 0; kk < 4; ++kk) w4[kk] = *(const float4*)&Wb[buf][g * 4 + kk][tx * 4];
#pragma unroll
            for (int r = 0; r < 4; ++r) {
                float4 a = *(const float4*)&At[ty * 4 + r][c * 16 + g * 4];
                float ar[4] = {a.x, a.y, a.z, a.w};
#pragma unroll
                for (int kk = 0; kk < 4; ++kk) {
                    acc[r][0] = fmaf(ar[kk], w4[kk].x, acc[r][0]);
                    acc[r][1] = fmaf(ar[kk], w4[kk].y, acc[r][1]);
                    acc[r][2] = fmaf(ar[kk], w4[kk].z, acc[r][2]);
                    acc[r][3] = fmaf(ar[kk], w4[kk].w, acc[r][3]);
                }
            }
        }
        if (c < 7) ((float4*)&Wb[buf ^ 1][0][0])[t] = wnext;
        __syncthreads();
    }

    const int c0 = tx * 4;
    float bvv[4];
#pragma unroll
    for (int c = 0; c < 4; ++c) bvv[c] = bias[c0 + c];
#pragma unroll
    for (int r = 0; r < 4; ++r) {
        int row = row0 + ty * 4 + r;
        if (row < n) {
            float4 o;
            o.x = acc[r][0] + bvv[0]; o.y = acc[r][1] + bvv[1];
            o.z = acc[r][2] + bvv[2]; o.w = acc[r][3] + bvv[3];
            *(float4*)&H[(size_t)row * 128 + c0] = o;
        }
    }
}

__global__ void scale_init(const float* __restrict__ h, float* __restrict__ z,
                           const float* __restrict__ eps, int layer, int n4)
{
    const float s = 1.0f + eps[layer];
    int i = blockIdx.x * blockDim.x + threadIdx.x;
    const int stride = gridDim.x * blockDim.x;
    const float4* h4 = (const float4*)h;
    float4* z4 = (float4*)z;
    for (; i < n4; i += stride) {
        float4 v = h4[i];
        v.x *= s; v.y *= s; v.z *= s; v.w *= s;
        z4[i] = v;
    }
}

__global__ __launch_bounds__(256) void edge_atomic(
    const float* __restrict__ h, const int* __restrict__ ei,
    const float* __restrict__ eattr, const float* __restrict__ eatten,
    const float* __restrict__ W_ee, const float* __restrict__ b_ee,
    float* __restrict__ Z, int E)
{
    __shared__ float Wee[16][128];
    __shared__ float bee[128];
    const int t = threadIdx.x;
    const float4* We4 = (const float4*)W_ee;
    float4* Ws4 = (float4*)&Wee[0][0];
#pragma unroll
    for (int i = 0; i < 2; ++i) Ws4[t + 256 * i] = We4[t + 256 * i];
    if (t < 128) bee[t] = b_ee[t];
    __syncthreads();

    const int lane = t & 63;
    const int c = lane * 2;
    const long wid = (long)blockIdx.x * 4 + (t >> 6);
    const long nw = (long)gridDim.x * 4;
    for (long e = wid; e < E; e += nw) {
        const int src = ei[e];
        const int dst = ei[E + e];
        const float att = eatten[e];
        union { float4 v4[4]; float f[16]; } ea;
        const float4* eap = (const float4*)(eattr + e * 16);
        ea.v4[0] = eap[0]; ea.v4[1] = eap[1]; ea.v4[2] = eap[2]; ea.v4[3] = eap[3];
        float2 hv = *(const float2*)&h[(size_t)src * 128 + c];
        float e0 = bee[c], e1 = bee[c + 1];
#pragma unroll
        for (int k = 0; k < 16; ++k) {
            float2 w = *(const float2*)&Wee[k][c];
            e0 = fmaf(ea.f[k], w.x, e0);
            e1 = fmaf(ea.f[k], w.y, e1);
        }
        float m0 = fmaxf(hv.x + e0, 0.f) * att;
        float m1 = fmaxf(hv.y + e1, 0.f) * att;
        atomic_add2(&Z[(size_t)dst * 128 + c], m0, m1);
    }
}

__global__ __launch_bounds__(512, 4) void gemm_mlp(
    const float* __restrict__ Z,
    const float* __restrict__ W1, const float* __restrict__ b1,
    const float* __restrict__ gam, const float* __restrict__ bet,
    const float* __restrict__ mu, const float* __restrict__ var,
    const float* __restrict__ W2, const float* __restrict__ b2,
    float* __restrict__ H, int n)
{
    __shared__ float At[64][128];
    __shared__ float Wb[2][16][128];
    const int t = threadIdx.x;
    const int tx = t & 31, ty = t >> 5;

    const int row0 = blockIdx.x * 64;
    const int nrows = min(64, n - row0);
    const int lim = nrows * 32;
    const float4* Z4 = (const float4*)(Z + (size_t)row0 * 128);
    float4* At4 = (float4*)&At[0][0];
#pragma unroll
    for (int i = 0; i < 4; ++i) {
        int idx = t + 512 * i;
        if (idx < lim) At4[idx] = Z4[idx];
    }
    const float4* W14 = (const float4*)W1;
    ((float4*)&Wb[0][0][0])[t] = W14[t];
    __syncthreads();

    float acc[4][4] = {};
    for (int c = 0; c < 8; ++c) {
        const int buf = c & 1;
        float4 wnext;
        if (c < 7) wnext = W14[(c + 1) * 512 + t];
#pragma unroll
        for (int g = 0; g < 4; ++g) {
            float4 w4[4];
#pragma unroll
            for (int kk = 0; kk < 4; ++kk) w4[kk] = *(const float4*)&Wb[buf][g * 4 + kk][tx * 4];
#pragma unroll
            for (int r = 0; r < 4; ++r) {
                float4 a = *(const float4*)&At[ty * 4 + r][c * 16 + g * 4];
                float ar[4] = {a.x, a.y, a.z, a.w};
#pragma unroll
                for (int kk = 0; kk < 4; ++kk) {
                    acc[r][0] = fmaf(ar[kk], w4[kk].x, acc[r][0]);
                    acc[r][1] = fmaf(ar[kk], w4[kk].y, acc[r][1]);
                    acc[r][2] = fmaf(ar[kk], w4[kk].z, acc[r][2]);
                    acc[r][3] = fmaf(ar[kk], w4[kk].w, acc[r][3]);
                }
            }
        }
        if (c < 7) ((float4*)&Wb[buf ^ 1][0][0])[t] = wnext;
        __syncthreads();
    }

    const int c0 = tx * 4;
    const float4* W24 = (const float4*)W2;
    float4 w2pre = W24[t];
    {
        float b1v[4], scv[4], shv[4];
#pragma unroll
        for (int cl = 0; cl < 4; ++cl) {
            b1v[cl] = b1[c0 + cl];
            float s = gam[c0 + cl] * rsqrtf(var[c0 + cl] + 1e-5f);
            scv[cl] = s;
            shv[cl] = bet[c0 + cl] - mu[c0 + cl] * s;
        }
#pragma unroll
        for (int r = 0; r < 4; ++r) {
            float4 y;
            y.x = fmaxf(fmaf(acc[r][0] + b1v[0], scv[0], shv[0]), 0.f);
            y.y = fmaxf(fmaf(acc[r][1] + b1v[1], scv[1], shv[1]), 0.f);
            y.z = fmaxf(fmaf(acc[r][2] + b1v[2], scv[2], shv[2]), 0.f);
            y.w = fmaxf(fmaf(acc[r][3] + b1v[3], scv[3], shv[3]), 0.f);
            *(float4*)&At[ty * 4 + r][c0] = y;
            acc[r][0] = 0.f; acc[r][1] = 0.f; acc[r][2] = 0.f; acc[r][3] = 0.f;
        }
    }
    ((float4*)&Wb[0][0][0])[t] = w2pre;
    __syncthreads();

    for (int c = 0; c < 8; ++c) {
        const int buf = c & 1;
        float4 wnext;
        if (c < 7) wnext = W24[(c + 1) * 512 + t];
#pragma unroll
        for (int g = 0; g < 4; ++g) {
            float4 w4[4];
#pragma unroll
            for (int kk = 0; kk < 4; ++kk) w4[kk] = *(const float4*)&Wb[buf][g * 4 + kk][tx * 4];
#pragma unroll
            for (int r = 0; r < 4; ++r) {
                float4 a = *(const float4*)&At[ty * 4 + r][c * 16 + g * 4];
                float ar[4] = {a.x, a.y, a.z, a.w};
#pragma unroll
                for (int kk = 0; kk < 4; ++kk) {
                    acc[r][0] = fmaf(ar[kk], w4[kk].x, acc[r][0]);
                    acc[r][1] = fmaf(ar[kk], w4[kk].y, acc[r][1]);
                    acc[r][2] = fmaf(ar[kk], w4[kk].z, acc[r][2]);
                    acc[r][3] = fmaf(ar[kk], w4[kk].w, acc[r][3]);
                }
            }
        }
        if (c < 7) ((float4*)&Wb[buf ^ 1][0][0])[t] = wnext;
        __syncthreads();
    }

    float b2v[4];
#pragma unroll
    for (int cl = 0; cl < 4; ++cl) b2v[cl] = b2[c0 + cl];
#pragma unroll
    for (int r = 0; r < 4; ++r) {
        int row = row0 + ty * 4 + r;
        if (row < n) {
            float4 o;
            o.x = fmaxf(acc[r][0] + b2v[0], 0.f);
            o.y = fmaxf(acc[r][1] + b2v[1], 0.f);
            o.z = fmaxf(acc[r][2] + b2v[2], 0.f);
            o.w = fmaxf(acc[r][3] + b2v[3], 0.f);
            *(float4*)&H[(size_t)row * 128 + c0] = o;
        }
    }
}

extern "C" void kernel_launch(void* const* d_in, const int* in_sizes, int n_in,
                              void* d_out, int out_size, void* d_ws, size_t ws_size,
                              hipStream_t stream)
{
    const float* x      = (const float*)d_in[0];
    const int*   ei     = (const int*)d_in[1];
    // d_in[2] = batch (unused)
    const float* eattr  = (const float*)d_in[3];
    const float* eatten = (const float*)d_in[4];
    const float* W_enc  = (const float*)d_in[5];
    const float* b_enc  = (const float*)d_in[6];
    const float* W_ee   = (const float*)d_in[7];
    const float* b_ee   = (const float*)d_in[8];
    const float* eps    = (const float*)d_in[9];
    const float* W1     = (const float*)d_in[10];
    const float* b1     = (const float*)d_in[11];
    const float* gam    = (const float*)d_in[12];
    const float* bet    = (const float*)d_in[13];
    const float* mu     = (const float*)d_in[14];
    const float* var    = (const float*)d_in[15];
    const float* W2     = (const float*)d_in[16];
    const float* b2     = (const float*)d_in[17];

    const int N = in_sizes[0] / 128;
    const int E = in_sizes[1] / 2;
    const int L = in_sizes[9];
    const int Scap = E + N;      // max padded slots

    float* hout = (float*)d_out;   // final f32 output

    // workspace layout (main path). x16 aliases z16 (x16 dead after enc).
    char* p = (char*)d_ws;
    _Float16* z16 = (_Float16*)p;       p += ((size_t)N * 128 * 2 + 255) & ~(size_t)255;
    _Float16* h16 = (_Float16*)p;       p += ((size_t)N * 128 * 2 + 255) & ~(size_t)255;
    int* off  = (int*)p;                p += 4 * (size_t)(N + 1);
    int* cur  = (int*)p;                p += 4 * (size_t)N;
    int* cnt  = (int*)p;                p += 4 * (size_t)N;
    int* bsum = (int*)p;                p += 4 * 1024;
    int* eids = (int*)p;                p += 4 * (size_t)Scap;
    p = (char*)(((uintptr_t)p + 255) & ~(uintptr_t)255);
    float2* sat = (float2*)p;           p += 8 * (size_t)Scap;
    p = (char*)(((uintptr_t)p + 255) & ~(uintptr_t)255);
    uint32_t* eab32 = (uint32_t*)p;     p += 256 * (size_t)((Scap + 1) / 2);
    p = (char*)(((uintptr_t)p + 255) & ~(uintptr_t)255);
    _Float16* Wpk = (_Float16*)p;       p += (2 * (size_t)L + 1) * 32 * 512 * 2;
    const size_t need_main = (size_t)(p - (char*)d_ws);

    const bool use_main = ws_size >= need_main;
    const int tiles = (N + 63) / 64;
    const int NB = (N + 1023) / 1024;

    if (use_main) {
        _Float16* x16 = z16;   // alias: x16 dead once layer-0 agg writes z16

        init_arrays<<<1024, 256, 0, stream>>>(cnt, N, eids, Scap);
        hist_kernel<<<1024, 256, 0, stream>>>(ei, cnt, E);
        scan_pass1<<<NB, 256, 0, stream>>>(cnt, bsum, N);
        scan_pass2<<<1, 256, 0, stream>>>(bsum, off, NB, N);
        scan_pass3<<<NB, 256, 0, stream>>>(cnt, bsum, off, cur, N);
        scatter_kernel<<<1024, 256, 0, stream>>>(ei, cur, eids, E);
        eabuild_mfma<<<(Scap + 255) / 256, 256, 0, stream>>>(
            eids, eattr, ei, eatten, W_ee, b_ee, off + N, eab32, sat, Scap);
        prepack_w<<<((2 * L + 1) * 32 * 64 + 255) / 256, 256, 0, stream>>>(
            W1, W2, W_enc, Wpk, L);

        cvt_f16<<<2048, 256, 0, stream>>>(x, x16, N * 128 / 8);
        enc_mfma<<<tiles, 256, 0, stream>>>(
            x16, Wpk + (size_t)(2 * L) * 32 * 512, b_enc, h16, N);

        for (int i = 0; i < L; ++i) {
            agg_f8<<<(N + 3) / 4, 256, 0, stream>>>(
                h16, sat, eab32, off, z16, eps, i, N);
            mlp_mfma<<<tiles, 256, 0, stream>>>(
                z16,
                Wpk + (size_t)i * 32 * 512, b1 + i * 128,
                gam + i * 128, bet + i * 128, mu + i * 128, var + i * 128,
                Wpk + (size_t)(L + i) * 32 * 512, b2 + i * 128,
                h16, hout, (i == L - 1) ? 1 : 0, N);
        }
        return;
    }

    // fallback: f32 atomic tier (zbuf at ws start)
    float* zbuf = (float*)d_ws;
    float* h = hout;
    gemm_enc<<<tiles, 512, 0, stream>>>(x, W_enc, b_enc, h, N);
    for (int i = 0; i < L; ++i) {
        scale_init<<<2048, 256, 0, stream>>>(h, zbuf, eps, i, N * 128 / 4);
        edge_atomic<<<2048, 256, 0, stream>>>(h, ei, eattr, eatten, W_ee, b_ee, zbuf, E);
        gemm_mlp<<<tiles, 512, 0, stream>>>(
            zbuf, W1 + (size_t)i * 128 * 128, b1 + i * 128,
            gam + i * 128, bet + i * 128, mu + i * 128, var + i * 128,
            W2 + (size_t)i * 128 * 128, b2 + i * 128,
            h, N);
    }
}

// Round 17
// 399.695 us; speedup vs baseline: 1.6570x; 1.0231x over previous
//
#include <hip/hip_runtime.h>
#include <hip/hip_fp16.h>
#include <cstdint>
#include <cstddef>

// ---------------------------------------------------------------------------
// GIN (GINEConv x3) forward. f32 in/out; f16 h/z; FP8(e4m3) precomputed ea.
//   x16 = f16(x); h16 = x16@W_enc + b (enc_mfma)
//   CSR (deg padded even) -> eabuild_mfma: sat{src,att} + eab8 (fp8 ea,
//     pair-interleaved; ea on the MFMA pipe, staged via f16 LDS)
//   per layer: agg_f8 (h16 gather + fp8 ea decode) -> z16
//              mlp_mfma (16x16x32 f16) -> h16 (last layer: f32 d_out)
// ---------------------------------------------------------------------------

typedef _Float16 f16x8 __attribute__((ext_vector_type(8)));
typedef _Float16 f16x2 __attribute__((ext_vector_type(2)));
typedef float    f32x4 __attribute__((ext_vector_type(4)));
typedef float    f32x2 __attribute__((ext_vector_type(2)));

// ---- fp8 e4m3 pack/unpack with compile-safe fallback ----------------------
__device__ inline uint32_t pack_fp8_pair(float a, float b) {
#if __has_builtin(__builtin_amdgcn_cvt_pk_fp8_f32)
    return (uint32_t)__builtin_amdgcn_cvt_pk_fp8_f32(a, b, 0, false) & 0xFFFFu;
#else
    auto enc = [](float x) -> uint32_t {
        uint32_t s = (x < 0.f) ? 0x80u : 0u;
        float ax = fabsf(x);
        if (!(ax >= 1.953125e-3f)) {
            int mi = (int)(ax * 512.f + 0.5f);
            if (mi > 7) mi = 7;
            return s | (uint32_t)mi;
        }
        ax = fminf(ax, 448.f);
        int e; float m = frexpf(ax, &e);
        int E = e - 1 + 7;
        int mi = (int)((m * 2.f - 1.f) * 8.f + 0.5f);
        if (mi == 8) { mi = 0; ++E; }
        if (E > 15 || (E == 15 && mi == 7)) { E = 15; mi = 6; }
        return s | ((uint32_t)E << 3) | (uint32_t)mi;
    };
    return enc(a) | (enc(b) << 8);
#endif
}

template <bool HIGH>
__device__ inline f32x2 unpack_fp8_pair(uint32_t w) {
#if __has_builtin(__builtin_amdgcn_cvt_pk_f32_fp8)
    return __builtin_amdgcn_cvt_pk_f32_fp8((int)w, HIGH);
#else
    auto dec = [](uint32_t v) -> float {
        uint32_t s = v >> 7, e = (v >> 3) & 0xF, m = v & 7;
        float r = (e == 0) ? ldexpf((float)m, -9)
                           : ldexpf(1.f + (float)m / 8.f, (int)e - 7);
        return s ? -r : r;
    };
    uint32_t b0 = HIGH ? ((w >> 16) & 0xFF) : (w & 0xFF);
    uint32_t b1 = HIGH ? ((w >> 24) & 0xFF) : ((w >> 8) & 0xFF);
    return (f32x2){dec(b0), dec(b1)};
#endif
}

// ---- packed-f32x2 atomic with compile-safe fallback (fallback tier only) ---
template <class T>
__device__ inline auto add2_impl(T* p, T v, int)
    -> decltype(unsafeAtomicAdd(p, v), void()) {
    unsafeAtomicAdd(p, v);
}
template <class T>
__device__ inline void add2_impl(T* p, T v, long) {
    unsafeAtomicAdd(&p->x, v.x);
    unsafeAtomicAdd(&p->y, v.y);
}
__device__ inline void atomic_add2(float* p, float x, float y) {
    add2_impl(reinterpret_cast<float2*>(p), make_float2(x, y), 0);
}

// ---------------------------------------------------------------------------
// CSR build
// ---------------------------------------------------------------------------
__global__ void init_arrays(int* __restrict__ cnt, int N, int* __restrict__ eids, int S)
{
    int i = blockIdx.x * blockDim.x + threadIdx.x;
    const int st = gridDim.x * blockDim.x;
    for (int j = i; j < N; j += st) cnt[j] = 0;
    for (int j = i; j < S; j += st) eids[j] = -1;
}

__global__ void hist_kernel(const int* __restrict__ ei, int* __restrict__ cnt, int E)
{
    int i = blockIdx.x * blockDim.x + threadIdx.x;
    const int st = gridDim.x * blockDim.x;
    for (; i < E; i += st) atomicAdd(&cnt[ei[E + i]], 1);
}

__global__ __launch_bounds__(256) void scan_pass1(
    const int* __restrict__ cnt, int* __restrict__ bsum, int N)
{
    __shared__ int part[256];
    const int t = threadIdx.x;
    const int base = blockIdx.x * 1024 + t * 4;
    int s = 0;
#pragma unroll
    for (int j = 0; j < 4; ++j) {
        int idx = base + j;
        if (idx < N) { int v = cnt[idx]; s += v + (v & 1); }
    }
    part[t] = s;
    __syncthreads();
    for (int d = 128; d > 0; d >>= 1) {
        if (t < d) part[t] += part[t + d];
        __syncthreads();
    }
    if (t == 0) bsum[blockIdx.x] = part[0];
}

__global__ __launch_bounds__(256) void scan_pass2(
    int* __restrict__ bsum, int* __restrict__ off, int NB, int N)
{
    __shared__ int sb[1024];
    const int t = threadIdx.x;
    for (int i = t; i < NB; i += 256) sb[i] = bsum[i];
    __syncthreads();
    if (t == 0) {
        int run = 0;
        for (int i = 0; i < NB; ++i) { int v = sb[i]; sb[i] = run; run += v; }
        off[N] = run;          // total padded slots S
    }
    __syncthreads();
    for (int i = t; i < NB; i += 256) bsum[i] = sb[i];
}

__global__ __launch_bounds__(256) void scan_pass3(
    const int* __restrict__ cnt, const int* __restrict__ bsum,
    int* __restrict__ off, int* __restrict__ cur, int N)
{
    __shared__ int part[256];
    const int t = threadIdx.x;
    const int base = blockIdx.x * 1024 + t * 4;
    int pv[4]; int s = 0;
#pragma unroll
    for (int j = 0; j < 4; ++j) {
        int idx = base + j;
        int v = (idx < N) ? cnt[idx] : 0;
        pv[j] = v + (v & 1);
        s += pv[j];
    }
    part[t] = s;
    __syncthreads();
    for (int d = 1; d < 256; d <<= 1) {
        int x = (t >= d) ? part[t - d] : 0;
        __syncthreads();
        part[t] += x;
        __syncthreads();
    }
    int run = bsum[blockIdx.x] + part[t] - s;
#pragma unroll
    for (int j = 0; j < 4; ++j) {
        int idx = base + j;
        if (idx < N) { off[idx] = run; cur[idx] = run; }
        run += pv[j];
    }
}

__global__ void scatter_kernel(const int* __restrict__ ei, int* __restrict__ cur,
                               int* __restrict__ eids, int E)
{
    int i = blockIdx.x * blockDim.x + threadIdx.x;
    const int st = gridDim.x * blockDim.x;
    for (; i < E; i += st) {
        int pos = atomicAdd(&cur[ei[E + i]], 1);
        eids[pos] = i;
    }
}

// ---------------------------------------------------------------------------
// eabuild_mfma: per 256-slot block:
//   stage eids; write sat{src,att}; stage attr rows as f16 in LDS;
//   per wave: 4 tiles of 16 slots, ea = attr@W_ee via 8 MFMAs -> f16 LDS;
//   pack (ea + b_ee) to fp8, pair-interleaved u32 writes.
// LDS ~26 KB -> 6 blocks/CU.
// ---------------------------------------------------------------------------
__global__ __launch_bounds__(256) void eabuild_mfma(
    const int* __restrict__ eids, const float* __restrict__ eattr,
    const int* __restrict__ ei, const float* __restrict__ eatten,
    const float* __restrict__ W_ee, const float* __restrict__ b_ee,
    const int* __restrict__ offN, uint32_t* __restrict__ eab32,
    float2* __restrict__ sat, int Scap)
{
    __shared__ int      se[256];              // 1 KB
    __shared__ _Float16 sattr16[256][16];     // 8 KB
    __shared__ _Float16 eaL[4][16][132];      // 16.5 KB (per-wave f16 tiles)
    const int t = threadIdx.x;
    const int lane = t & 63;
    const int w = t >> 6;
    const int lr = lane & 15;
    const int lg = lane >> 4;
    const int c = lane * 2;

    const int S = *offN;
    const int base = blockIdx.x * 256;
    const int n = min(256, S - base);
    if (n <= 0) return;

    // B fragments of W_ee: col = tc*16+lr, k = lg*8+i (k<16 real, else 0)
    f16x8 bfrag[8];
#pragma unroll
    for (int tc = 0; tc < 8; ++tc) {
        f16x8 b = {};
        if (lg < 2) {
#pragma unroll
            for (int i = 0; i < 8; ++i)
                b[i] = (_Float16)W_ee[(lg * 8 + i) * 128 + tc * 16 + lr];
        }
        bfrag[tc] = b;
    }
    const float2 bv = *(const float2*)&b_ee[c];

    if (t < n) se[t] = eids[base + t];
    __syncthreads();

    // sat write + attr -> f16 LDS (zero rows >= n)
    if (t < n) {
        const int eid = se[t];
        float2 v;
        f16x8 lo = {}, hi = {};
        if (eid >= 0) {
            v.x = __int_as_float(ei[eid]); v.y = eatten[eid];
            const float4* ep = (const float4*)(eattr + (size_t)eid * 16);
            float4 e0 = ep[0], e1 = ep[1], e2 = ep[2], e3 = ep[3];
            lo = (f16x8){(_Float16)e0.x, (_Float16)e0.y, (_Float16)e0.z, (_Float16)e0.w,
                         (_Float16)e1.x, (_Float16)e1.y, (_Float16)e1.z, (_Float16)e1.w};
            hi = (f16x8){(_Float16)e2.x, (_Float16)e2.y, (_Float16)e2.z, (_Float16)e2.w,
                         (_Float16)e3.x, (_Float16)e3.y, (_Float16)e3.z, (_Float16)e3.w};
        } else {
            v.x = __int_as_float(0); v.y = 0.f;
        }
        sat[base + t] = v;
        *(f16x8*)&sattr16[t][0] = lo;
        *(f16x8*)&sattr16[t][8] = hi;
    } else {
        *(f16x8*)&sattr16[t][0] = (f16x8){};
        *(f16x8*)&sattr16[t][8] = (f16x8){};
    }
    __syncthreads();

    // per wave: 4 tiles of 16 slots
#pragma unroll
    for (int k = 0; k < 4; ++k) {
        const int tb = w * 64 + k * 16;          // tile base (block-local)
        if (tb >= n) break;
        f16x8 af = {};
        if (lg < 2)
            af = *(const f16x8*)&sattr16[tb + lr][lg * 8];
#pragma unroll
        for (int tc = 0; tc < 8; ++tc) {
            f32x4 acc = __builtin_amdgcn_mfma_f32_16x16x32_f16(
                af, bfrag[tc], (f32x4){0.f, 0.f, 0.f, 0.f}, 0, 0, 0);
#pragma unroll
            for (int j = 0; j < 4; ++j)
                eaL[w][lg * 4 + j][tc * 16 + lr] = (_Float16)acc[j];
        }
        // pack lane's 2 cols for 8 slot-pairs (n even -> no pair straddle)
#pragma unroll
        for (int pp = 0; pp < 8; ++pp) {
            const int s0 = tb + 2 * pp;
            if (s0 >= n) break;
            f16x2 ea0 = *(const f16x2*)&eaL[w][2 * pp][c];
            f16x2 ea1 = *(const f16x2*)&eaL[w][2 * pp + 1][c];
            uint32_t p0 = pack_fp8_pair((float)ea0.x + bv.x, (float)ea0.y + bv.y);
            uint32_t p1 = pack_fp8_pair((float)ea1.x + bv.x, (float)ea1.y + bv.y);
            eab32[(size_t)((base + s0) >> 1) * 64 + lane] = p0 | (p1 << 16);
        }
    }
}

// ---------------------------------------------------------------------------
// prepack W1/W2/W_enc into MFMA B-fragment order (f16).
// ---------------------------------------------------------------------------
__global__ void prepack_w(const float* __restrict__ W1, const float* __restrict__ W2,
                          const float* __restrict__ Wenc,
                          _Float16* __restrict__ Wpk, int L)
{
    int tid = blockIdx.x * blockDim.x + threadIdx.x;
    const int total = (2 * L + 1) * 32 * 64;
    if (tid >= total) return;
    const int lane = tid & 63;
    const int f = (tid >> 6) & 31;
    const int lm = tid >> 11;
    const int kb = f >> 3, tc = f & 7;
    const float* src = (lm < L) ? (W1 + (size_t)lm * 16384)
                    : (lm < 2 * L) ? (W2 + (size_t)(lm - L) * 16384)
                    : Wenc;
    _Float16* dst = Wpk + ((size_t)lm * 32 + f) * 512 + lane * 8;
#pragma unroll
    for (int i = 0; i < 8; ++i) {
        const int k = kb * 32 + (lane >> 4) * 8 + i;
        const int col = tc * 16 + (lane & 15);
        dst[i] = (_Float16)src[k * 128 + col];
    }
}

// f32 -> f16 bulk convert (8 elems/thread)
__global__ void cvt_f16(const float* __restrict__ x, _Float16* __restrict__ y, int n8)
{
    int i = blockIdx.x * blockDim.x + threadIdx.x;
    const int st = gridDim.x * blockDim.x;
    for (; i < n8; i += st) {
        float4 a = ((const float4*)x)[2 * i];
        float4 b = ((const float4*)x)[2 * i + 1];
        f16x8 v = {(_Float16)a.x, (_Float16)a.y, (_Float16)a.z, (_Float16)a.w,
                   (_Float16)b.x, (_Float16)b.y, (_Float16)b.z, (_Float16)b.w};
        ((f16x8*)y)[i] = v;
    }
}

// ---------------------------------------------------------------------------
// Encoder MFMA: h16 = x16 @ W_enc + b_enc.
// ---------------------------------------------------------------------------
__global__ __launch_bounds__(256) void enc_mfma(
    const _Float16* __restrict__ x16, const _Float16* __restrict__ Wpk,
    const float* __restrict__ bias, _Float16* __restrict__ h16, int n)
{
    const int t = threadIdx.x;
    const int lane = t & 63;
    const int w = t >> 6;
    const int row0 = blockIdx.x * 64;
    const int lr = lane & 15;
    const int lg = lane >> 4;

    f32x4 acc[8];
#pragma unroll
    for (int tc = 0; tc < 8; ++tc) acc[tc] = (f32x4){0.f, 0.f, 0.f, 0.f};
    const int arow = min(row0 + w * 16 + lr, n - 1);
#pragma unroll
    for (int kb = 0; kb < 4; ++kb) {
        f16x8 a = *(const f16x8*)&x16[(size_t)arow * 128 + kb * 32 + lg * 8];
#pragma unroll
        for (int tc = 0; tc < 8; ++tc) {
            f16x8 b = *(const f16x8*)&Wpk[((kb * 8 + tc) * 64 + lane) * 8];
            acc[tc] = __builtin_amdgcn_mfma_f32_16x16x32_f16(a, b, acc[tc], 0, 0, 0);
        }
    }
#pragma unroll
    for (int tc = 0; tc < 8; ++tc) {
        const int col = tc * 16 + lr;
        const float bb = bias[col];
#pragma unroll
        for (int j = 0; j < 4; ++j) {
            const int row = row0 + w * 16 + lg * 4 + j;
            if (row < n)
                h16[(size_t)row * 128 + col] = (_Float16)(acc[tc][j] + bb);
        }
    }
}

// ---------------------------------------------------------------------------
// Aggregation: one wave per node, lane owns 2 cols. h16 gather + fp8 ea.
// ---------------------------------------------------------------------------
__global__ __launch_bounds__(256) void agg_f8(
    const _Float16* __restrict__ h16, const float2* __restrict__ sat,
    const uint32_t* __restrict__ eab8, const int* __restrict__ off,
    _Float16* __restrict__ z16, const float* __restrict__ eps, int layer, int N)
{
    const int t = threadIdx.x;
    const int v = blockIdx.x * 4 + (t >> 6);
    if (v >= N) return;
    const int lane = t & 63;
    const int c = lane * 2;

    const int e0 = off[v], e1 = off[v + 1];   // even-aligned, even length
    float a0 = 0.f, a1 = 0.f;
    int e = e0;
    for (; e + 8 <= e1; e += 8) {
        float4 sa[2];
        sa[0] = *(const float4*)&sat[e];
        sa[1] = *(const float4*)&sat[e + 2];
        float4 sb[2];
        sb[0] = *(const float4*)&sat[e + 4];
        sb[1] = *(const float4*)&sat[e + 6];
        uint32_t eb[4];
#pragma unroll
        for (int j = 0; j < 4; ++j)
            eb[j] = eab8[(size_t)((e >> 1) + j) * 64 + lane];
        uint32_t hv[8];
        hv[0] = *(const uint32_t*)&h16[(size_t)__float_as_int(sa[0].x) * 128 + c];
        hv[1] = *(const uint32_t*)&h16[(size_t)__float_as_int(sa[0].z) * 128 + c];
        hv[2] = *(const uint32_t*)&h16[(size_t)__float_as_int(sa[1].x) * 128 + c];
        hv[3] = *(const uint32_t*)&h16[(size_t)__float_as_int(sa[1].z) * 128 + c];
        hv[4] = *(const uint32_t*)&h16[(size_t)__float_as_int(sb[0].x) * 128 + c];
        hv[5] = *(const uint32_t*)&h16[(size_t)__float_as_int(sb[0].z) * 128 + c];
        hv[6] = *(const uint32_t*)&h16[(size_t)__float_as_int(sb[1].x) * 128 + c];
        hv[7] = *(const uint32_t*)&h16[(size_t)__float_as_int(sb[1].z) * 128 + c];
#pragma unroll
        for (int j = 0; j < 4; ++j) {
            const float4 s4 = (j < 2) ? sa[j] : sb[j - 2];
            f32x2 ev = unpack_fp8_pair<false>(eb[j]);
            f32x2 od = unpack_fp8_pair<true>(eb[j]);
            __half2 h0 = *reinterpret_cast<const __half2*>(&hv[2 * j]);
            __half2 h1 = *reinterpret_cast<const __half2*>(&hv[2 * j + 1]);
            a0 += fmaxf(__half2float(__low2half(h0))  + ev[0], 0.f) * s4.y;
            a1 += fmaxf(__half2float(__high2half(h0)) + ev[1], 0.f) * s4.y;
            a0 += fmaxf(__half2float(__low2half(h1))  + od[0], 0.f) * s4.w;
            a1 += fmaxf(__half2float(__high2half(h1)) + od[1], 0.f) * s4.w;
        }
    }
    for (; e < e1; e += 2) {
        float4 sa = *(const float4*)&sat[e];
        uint32_t eb = eab8[(size_t)(e >> 1) * 64 + lane];
        uint32_t hv0 = *(const uint32_t*)&h16[(size_t)__float_as_int(sa.x) * 128 + c];
        uint32_t hv1 = *(const uint32_t*)&h16[(size_t)__float_as_int(sa.z) * 128 + c];
        f32x2 ev = unpack_fp8_pair<false>(eb);
        f32x2 od = unpack_fp8_pair<true>(eb);
        __half2 h0 = *reinterpret_cast<const __half2*>(&hv0);
        __half2 h1 = *reinterpret_cast<const __half2*>(&hv1);
        a0 += fmaxf(__half2float(__low2half(h0))  + ev[0], 0.f) * sa.y;
        a1 += fmaxf(__half2float(__high2half(h0)) + ev[1], 0.f) * sa.y;
        a0 += fmaxf(__half2float(__low2half(h1))  + od[0], 0.f) * sa.w;
        a1 += fmaxf(__half2float(__high2half(h1)) + od[1], 0.f) * sa.w;
    }

    const float sc = 1.0f + eps[layer];
    uint32_t hvv = *(const uint32_t*)&h16[(size_t)v * 128 + c];
    __half2 hh = *reinterpret_cast<const __half2*>(&hvv);
    float zx = fmaf(sc, __half2float(__low2half(hh)), a0);
    float zy = fmaf(sc, __half2float(__high2half(hh)), a1);
    __half2 zz = __floats2half2_rn(zx, zy);
    *reinterpret_cast<__half2*>(&z16[(size_t)v * 128 + c]) = zz;
}

// ---------------------------------------------------------------------------
// MFMA MLP: out = relu( relu(BN(z16@W1+b1)) @ W2 + b2 ).
// last==0: write h16 (f16); last==1: write f32 H.
// ---------------------------------------------------------------------------
__global__ __launch_bounds__(256) void mlp_mfma(
    const _Float16* __restrict__ z16,
    const _Float16* __restrict__ W1pk, const float* __restrict__ b1,
    const float* __restrict__ gam, const float* __restrict__ bet,
    const float* __restrict__ mu, const float* __restrict__ var,
    const _Float16* __restrict__ W2pk, const float* __restrict__ b2,
    _Float16* __restrict__ h16out, float* __restrict__ H, int last, int n)
{
    __shared__ _Float16 Yt[64][136];   // padded: 2-way banks
    const int t = threadIdx.x;
    const int lane = t & 63;
    const int w = t >> 6;
    const int row0 = blockIdx.x * 64;
    const int lr = lane & 15;
    const int lg = lane >> 4;

    f32x4 acc[8];
#pragma unroll
    for (int tc = 0; tc < 8; ++tc) acc[tc] = (f32x4){0.f, 0.f, 0.f, 0.f};
    const int arow = min(row0 + w * 16 + lr, n - 1);
#pragma unroll
    for (int kb = 0; kb < 4; ++kb) {
        f16x8 a = *(const f16x8*)&z16[(size_t)arow * 128 + kb * 32 + lg * 8];
#pragma unroll
        for (int tc = 0; tc < 8; ++tc) {
            f16x8 b = *(const f16x8*)&W1pk[((kb * 8 + tc) * 64 + lane) * 8];
            acc[tc] = __builtin_amdgcn_mfma_f32_16x16x32_f16(a, b, acc[tc], 0, 0, 0);
        }
    }
#pragma unroll
    for (int tc = 0; tc < 8; ++tc) {
        const int col = tc * 16 + lr;
        const float s  = gam[col] * rsqrtf(var[col] + 1e-5f);
        const float sh = bet[col] - mu[col] * s;
        const float bb = b1[col];
#pragma unroll
        for (int j = 0; j < 4; ++j) {
            float y = fmaxf(fmaf(acc[tc][j] + bb, s, sh), 0.f);
            Yt[w * 16 + lg * 4 + j][col] = (_Float16)y;
        }
    }
    __syncthreads();

#pragma unroll
    for (int tc = 0; tc < 8; ++tc) acc[tc] = (f32x4){0.f, 0.f, 0.f, 0.f};
#pragma unroll
    for (int kb = 0; kb < 4; ++kb) {
        f16x8 a = *(const f16x8*)&Yt[w * 16 + lr][kb * 32 + lg * 8];
#pragma unroll
        for (int tc = 0; tc < 8; ++tc) {
            f16x8 b = *(const f16x8*)&W2pk[((kb * 8 + tc) * 64 + lane) * 8];
            acc[tc] = __builtin_amdgcn_mfma_f32_16x16x32_f16(a, b, acc[tc], 0, 0, 0);
        }
    }
#pragma unroll
    for (int tc = 0; tc < 8; ++tc) {
        const int col = tc * 16 + lr;
        const float bb = b2[col];
#pragma unroll
        for (int j = 0; j < 4; ++j) {
            const int row = row0 + w * 16 + lg * 4 + j;
            if (row < n) {
                const float o = fmaxf(acc[tc][j] + bb, 0.f);
                if (last) H[(size_t)row * 128 + col] = o;
                else      h16out[(size_t)row * 128 + col] = (_Float16)o;
            }
        }
    }
}

// ---------------------------------------------------------------------------
// Fallback tier (f32 end-to-end): gemm_enc + scale_init + atomic + gemm_mlp
// ---------------------------------------------------------------------------
__global__ __launch_bounds__(512, 4) void gemm_enc(
    const float* __restrict__ A, const float* __restrict__ W,
    const float* __restrict__ bias, float* __restrict__ H, int n)
{
    __shared__ float At[64][128];
    __shared__ float Wb[2][16][128];
    const int t = threadIdx.x;
    const int tx = t & 31, ty = t >> 5;

    const int row0 = blockIdx.x * 64;
    const int nrows = min(64, n - row0);
    const int lim = nrows * 32;
    const float4* A4 = (const float4*)(A + (size_t)row0 * 128);
    float4* At4 = (float4*)&At[0][0];
#pragma unroll
    for (int i = 0; i < 4; ++i) {
        int idx = t + 512 * i;
        if (idx < lim) At4[idx] = A4[idx];
    }
    const float4* W4 = (const float4*)W;
    ((float4*)&Wb[0][0][0])[t] = W4[t];
    __syncthreads();

    float acc[4][4] = {};
    for (int c = 0; c < 8; ++c) {
        const int buf = c & 1;
        float4 wnext;
        if (c < 7) wnext = W4[(c + 1) * 512 + t];
#pragma unroll
        for (int g = 0; g < 4; ++g) {
            float4 w4[4];
#pragma unroll
            for (int kk = 0; kk < 4; ++kk) w4[kk] = *(const float4*)&Wb[buf][g * 4 + kk][tx * 4];
#pragma unroll
            for (int r = 0; r < 4; ++r) {
                float4 a = *(const float4*)&At[ty * 4 + r][c * 16 + g * 4];
                float ar[4] = {a.x, a.y, a.z, a.w};
#pragma unroll
                for (int kk = 0; kk < 4; ++kk) {
                    acc[r][0] = fmaf(ar[kk], w4[kk].x, acc[r][0]);
                    acc[r][1] = fmaf(ar[kk], w4[kk].y, acc[r][1]);
                    acc[r][2] = fmaf(ar[kk], w4[kk].z, acc[r][2]);
                    acc[r][3] = fmaf(ar[kk], w4[kk].w, acc[r][3]);
                }
            }
        }
        if (c < 7) ((float4*)&Wb[buf ^ 1][0][0])[t] = wnext;
        __syncthreads();
    }

    const int c0 = tx * 4;
    float bvv[4];
#pragma unroll
    for (int c = 0; c < 4; ++c) bvv[c] = bias[c0 + c];
#pragma unroll
    for (int r = 0; r < 4; ++r) {
        int row = row0 + ty * 4 + r;
        if (row < n) {
            float4 o;
            o.x = acc[r][0] + bvv[0]; o.y = acc[r][1] + bvv[1];
            o.z = acc[r][2] + bvv[2]; o.w = acc[r][3] + bvv[3];
            *(float4*)&H[(size_t)row * 128 + c0] = o;
        }
    }
}

__global__ void scale_init(const float* __restrict__ h, float* __restrict__ z,
                           const float* __restrict__ eps, int layer, int n4)
{
    const float s = 1.0f + eps[layer];
    int i = blockIdx.x * blockDim.x + threadIdx.x;
    const int stride = gridDim.x * blockDim.x;
    const float4* h4 = (const float4*)h;
    float4* z4 = (float4*)z;
    for (; i < n4; i += stride) {
        float4 v = h4[i];
        v.x *= s; v.y *= s; v.z *= s; v.w *= s;
        z4[i] = v;
    }
}

__global__ __launch_bounds__(256) void edge_atomic(
    const float* __restrict__ h, const int* __restrict__ ei,
    const float* __restrict__ eattr, const float* __restrict__ eatten,
    const float* __restrict__ W_ee, const float* __restrict__ b_ee,
    float* __restrict__ Z, int E)
{
    __shared__ float Wee[16][128];
    __shared__ float bee[128];
    const int t = threadIdx.x;
    const float4* We4 = (const float4*)W_ee;
    float4* Ws4 = (float4*)&Wee[0][0];
#pragma unroll
    for (int i = 0; i < 2; ++i) Ws4[t + 256 * i] = We4[t + 256 * i];
    if (t < 128) bee[t] = b_ee[t];
    __syncthreads();

    const int lane = t & 63;
    const int c = lane * 2;
    const long wid = (long)blockIdx.x * 4 + (t >> 6);
    const long nw = (long)gridDim.x * 4;
    for (long e = wid; e < E; e += nw) {
        const int src = ei[e];
        const int dst = ei[E + e];
        const float att = eatten[e];
        union { float4 v4[4]; float f[16]; } ea;
        const float4* eap = (const float4*)(eattr + e * 16);
        ea.v4[0] = eap[0]; ea.v4[1] = eap[1]; ea.v4[2] = eap[2]; ea.v4[3] = eap[3];
        float2 hv = *(const float2*)&h[(size_t)src * 128 + c];
        float e0 = bee[c], e1 = bee[c + 1];
#pragma unroll
        for (int k = 0; k < 16; ++k) {
            float2 w = *(const float2*)&Wee[k][c];
            e0 = fmaf(ea.f[k], w.x, e0);
            e1 = fmaf(ea.f[k], w.y, e1);
        }
        float m0 = fmaxf(hv.x + e0, 0.f) * att;
        float m1 = fmaxf(hv.y + e1, 0.f) * att;
        atomic_add2(&Z[(size_t)dst * 128 + c], m0, m1);
    }
}

__global__ __launch_bounds__(512, 4) void gemm_mlp(
    const float* __restrict__ Z,
    const float* __restrict__ W1, const float* __restrict__ b1,
    const float* __restrict__ gam, const float* __restrict__ bet,
    const float* __restrict__ mu, const float* __restrict__ var,
    const float* __restrict__ W2, const float* __restrict__ b2,
    float* __restrict__ H, int n)
{
    __shared__ float At[64][128];
    __shared__ float Wb[2][16][128];
    const int t = threadIdx.x;
    const int tx = t & 31, ty = t >> 5;

    const int row0 = blockIdx.x * 64;
    const int nrows = min(64, n - row0);
    const int lim = nrows * 32;
    const float4* Z4 = (const float4*)(Z + (size_t)row0 * 128);
    float4* At4 = (float4*)&At[0][0];
#pragma unroll
    for (int i = 0; i < 4; ++i) {
        int idx = t + 512 * i;
        if (idx < lim) At4[idx] = Z4[idx];
    }
    const float4* W14 = (const float4*)W1;
    ((float4*)&Wb[0][0][0])[t] = W14[t];
    __syncthreads();

    float acc[4][4] = {};
    for (int c = 0; c < 8; ++c) {
        const int buf = c & 1;
        float4 wnext;
        if (c < 7) wnext = W14[(c + 1) * 512 + t];
#pragma unroll
        for (int g = 0; g < 4; ++g) {
            float4 w4[4];
#pragma unroll
            for (int kk = 0; kk < 4; ++kk) w4[kk] = *(const float4*)&Wb[buf][g * 4 + kk][tx * 4];
#pragma unroll
            for (int r = 0; r < 4; ++r) {
                float4 a = *(const float4*)&At[ty * 4 + r][c * 16 + g * 4];
                float ar[4] = {a.x, a.y, a.z, a.w};
#pragma unroll
                for (int kk = 0; kk < 4; ++kk) {
                    acc[r][0] = fmaf(ar[kk], w4[kk].x, acc[r][0]);
                    acc[r][1] = fmaf(ar[kk], w4[kk].y, acc[r][1]);
                    acc[r][2] = fmaf(ar[kk], w4[kk].z, acc[r][2]);
                    acc[r][3] = fmaf(ar[kk], w4[kk].w, acc[r][3]);
                }
            }
        }
        if (c < 7) ((float4*)&Wb[buf ^ 1][0][0])[t] = wnext;
        __syncthreads();
    }

    const int c0 = tx * 4;
    const float4* W24 = (const float4*)W2;
    float4 w2pre = W24[t];
    {
        float b1v[4], scv[4], shv[4];
#pragma unroll
        for (int cl = 0; cl < 4; ++cl) {
            b1v[cl] = b1[c0 + cl];
            float s = gam[c0 + cl] * rsqrtf(var[c0 + cl] + 1e-5f);
            scv[cl] = s;
            shv[cl] = bet[c0 + cl] - mu[c0 + cl] * s;
        }
#pragma unroll
        for (int r = 0; r < 4; ++r) {
            float4 y;
            y.x = fmaxf(fmaf(acc[r][0] + b1v[0], scv[0], shv[0]), 0.f);
            y.y = fmaxf(fmaf(acc[r][1] + b1v[1], scv[1], shv[1]), 0.f);
            y.z = fmaxf(fmaf(acc[r][2] + b1v[2], scv[2], shv[2]), 0.f);
            y.w = fmaxf(fmaf(acc[r][3] + b1v[3], scv[3], shv[3]), 0.f);
            *(float4*)&At[ty * 4 + r][c0] = y;
            acc[r][0] = 0.f; acc[r][1] = 0.f; acc[r][2] = 0.f; acc[r][3] = 0.f;
        }
    }
    ((float4*)&Wb[0][0][0])[t] = w2pre;
    __syncthreads();

    for (int c = 0; c < 8; ++c) {
        const int buf = c & 1;
        float4 wnext;
        if (c < 7) wnext = W24[(c + 1) * 512 + t];
#pragma unroll
        for (int g = 0; g < 4; ++g) {
            float4 w4[4];
#pragma unroll
            for (int kk = 0; kk < 4; ++kk) w4[kk] = *(const float4*)&Wb[buf][g * 4 + kk][tx * 4];
#pragma unroll
            for (int r = 0; r < 4; ++r) {
                float4 a = *(const float4*)&At[ty * 4 + r][c * 16 + g * 4];
                float ar[4] = {a.x, a.y, a.z, a.w};
#pragma unroll
                for (int kk = 0; kk < 4; ++kk) {
                    acc[r][0] = fmaf(ar[kk], w4[kk].x, acc[r][0]);
                    acc[r][1] = fmaf(ar[kk], w4[kk].y, acc[r][1]);
                    acc[r][2] = fmaf(ar[kk], w4[kk].z, acc[r][2]);
                    acc[r][3] = fmaf(ar[kk], w4[kk].w, acc[r][3]);
                }
            }
        }
        if (c < 7) ((float4*)&Wb[buf ^ 1][0][0])[t] = wnext;
        __syncthreads();
    }

    float b2v[4];
#pragma unroll
    for (int cl = 0; cl < 4; ++cl) b2v[cl] = b2[c0 + cl];
#pragma unroll
    for (int r = 0; r < 4; ++r) {
        int row = row0 + ty * 4 + r;
        if (row < n) {
            float4 o;
            o.x = fmaxf(acc[r][0] + b2v[0], 0.f);
            o.y = fmaxf(acc[r][1] + b2v[1], 0.f);
            o.z = fmaxf(acc[r][2] + b2v[2], 0.f);
            o.w = fmaxf(acc[r][3] + b2v[3], 0.f);
            *(float4*)&H[(size_t)row * 128 + c0] = o;
        }
    }
}

extern "C" void kernel_launch(void* const* d_in, const int* in_sizes, int n_in,
                              void* d_out, int out_size, void* d_ws, size_t ws_size,
                              hipStream_t stream)
{
    const float* x      = (const float*)d_in[0];
    const int*   ei     = (const int*)d_in[1];
    // d_in[2] = batch (unused)
    const float* eattr  = (const float*)d_in[3];
    const float* eatten = (const float*)d_in[4];
    const float* W_enc  = (const float*)d_in[5];
    const float* b_enc  = (const float*)d_in[6];
    const float* W_ee   = (const float*)d_in[7];
    const float* b_ee   = (const float*)d_in[8];
    const float* eps    = (const float*)d_in[9];
    const float* W1     = (const float*)d_in[10];
    const float* b1     = (const float*)d_in[11];
    const float* gam    = (const float*)d_in[12];
    const float* bet    = (const float*)d_in[13];
    const float* mu     = (const float*)d_in[14];
    const float* var    = (const float*)d_in[15];
    const float* W2     = (const float*)d_in[16];
    const float* b2     = (const float*)d_in[17];

    const int N = in_sizes[0] / 128;
    const int E = in_sizes[1] / 2;
    const int L = in_sizes[9];
    const int Scap = E + N;      // max padded slots

    float* hout = (float*)d_out;   // final f32 output

    // workspace layout (main path). x16 aliases z16 (x16 dead after enc).
    char* p = (char*)d_ws;
    _Float16* z16 = (_Float16*)p;       p += ((size_t)N * 128 * 2 + 255) & ~(size_t)255;
    _Float16* h16 = (_Float16*)p;       p += ((size_t)N * 128 * 2 + 255) & ~(size_t)255;
    int* off  = (int*)p;                p += 4 * (size_t)(N + 1);
    int* cur  = (int*)p;                p += 4 * (size_t)N;
    int* cnt  = (int*)p;                p += 4 * (size_t)N;
    int* bsum = (int*)p;                p += 4 * 1024;
    int* eids = (int*)p;                p += 4 * (size_t)Scap;
    p = (char*)(((uintptr_t)p + 255) & ~(uintptr_t)255);
    float2* sat = (float2*)p;           p += 8 * (size_t)Scap;
    p = (char*)(((uintptr_t)p + 255) & ~(uintptr_t)255);
    uint32_t* eab32 = (uint32_t*)p;     p += 256 * (size_t)((Scap + 1) / 2);
    p = (char*)(((uintptr_t)p + 255) & ~(uintptr_t)255);
    _Float16* Wpk = (_Float16*)p;       p += (2 * (size_t)L + 1) * 32 * 512 * 2;
    const size_t need_main = (size_t)(p - (char*)d_ws);

    const bool use_main = ws_size >= need_main;
    const int tiles = (N + 63) / 64;
    const int NB = (N + 1023) / 1024;

    if (use_main) {
        _Float16* x16 = z16;   // alias: x16 dead once layer-0 agg writes z16

        init_arrays<<<1024, 256, 0, stream>>>(cnt, N, eids, Scap);
        hist_kernel<<<1024, 256, 0, stream>>>(ei, cnt, E);
        scan_pass1<<<NB, 256, 0, stream>>>(cnt, bsum, N);
        scan_pass2<<<1, 256, 0, stream>>>(bsum, off, NB, N);
        scan_pass3<<<NB, 256, 0, stream>>>(cnt, bsum, off, cur, N);
        scatter_kernel<<<1024, 256, 0, stream>>>(ei, cur, eids, E);
        eabuild_mfma<<<(Scap + 255) / 256, 256, 0, stream>>>(
            eids, eattr, ei, eatten, W_ee, b_ee, off + N, eab32, sat, Scap);
        prepack_w<<<((2 * L + 1) * 32 * 64 + 255) / 256, 256, 0, stream>>>(
            W1, W2, W_enc, Wpk, L);

        cvt_f16<<<2048, 256, 0, stream>>>(x, x16, N * 128 / 8);
        enc_mfma<<<tiles, 256, 0, stream>>>(
            x16, Wpk + (size_t)(2 * L) * 32 * 512, b_enc, h16, N);

        for (int i = 0; i < L; ++i) {
            agg_f8<<<(N + 3) / 4, 256, 0, stream>>>(
                h16, sat, eab32, off, z16, eps, i, N);
            mlp_mfma<<<tiles, 256, 0, stream>>>(
                z16,
                Wpk + (size_t)i * 32 * 512, b1 + i * 128,
                gam + i * 128, bet + i * 128, mu + i * 128, var + i * 128,
                Wpk + (size_t)(L + i) * 32 * 512, b2 + i * 128,
                h16, hout, (i == L - 1) ? 1 : 0, N);
        }
        return;
    }

    // fallback: f32 atomic tier (zbuf at ws start)
    float* zbuf = (float*)d_ws;
    float* h = hout;
    gemm_enc<<<tiles, 512, 0, stream>>>(x, W_enc, b_enc, h, N);
    for (int i = 0; i < L; ++i) {
        scale_init<<<2048, 256, 0, stream>>>(h, zbuf, eps, i, N * 128 / 4);
        edge_atomic<<<2048, 256, 0, stream>>>(h, ei, eattr, eatten, W_ee, b_ee, zbuf, E);
        gemm_mlp<<<tiles, 512, 0, stream>>>(
            zbuf, W1 + (size_t)i * 128 * 128, b1 + i * 128,
            gam + i * 128, bet + i * 128, mu + i * 128, var + i * 128,
            W2 + (size_t)i * 128 * 128, b2 + i * 128,
            h, N);
    }
}